// Round 1
// baseline (870.290 us; speedup 1.0000x reference)
//
#include <hip/hip_runtime.h>

static const long long N_ = 50000;
static const long long E_ = 800000;

__device__ __forceinline__ float lrelu(float x){ return x >= 0.f ? x : 0.2f*x; }
__device__ __forceinline__ unsigned fkey(float x){
  unsigned u = __float_as_uint(x);
  return (u & 0x80000000u) ? ~u : (u | 0x80000000u);
}
__device__ __forceinline__ float unfkey(unsigned k){
  return __uint_as_float((k & 0x80000000u) ? (k & 0x7fffffffu) : ~k);
}

// ---- column sums of edge_attr [E,4] -> sum_ea[4] ----
__global__ void k_sumea(const float* __restrict__ ea, float* __restrict__ sum_ea){
  __shared__ float lds[256];
  int t = threadIdx.x;
  long long total = E_*4;
  float s = 0.f;
  for (long long i = (long long)blockIdx.x*256 + t; i < total; i += (long long)gridDim.x*256)
    s += ea[i];                          // col = i&3 == t&3 (strides are %4==0)
  lds[t] = s; __syncthreads();
  for (int st=128; st>=4; st>>=1){ if (t<st) lds[t] += lds[t+st]; __syncthreads(); }
  if (t<4) atomicAdd(&sum_ea[t], lds[t]);
}

// ---- in-degree histogram over dst ----
__global__ void k_deg(const int* __restrict__ ei, int* __restrict__ deg){
  long long e = (long long)blockIdx.x*256 + threadIdx.x;
  if (e < E_) atomicAdd(&deg[ei[E_ + e]], 1);
}

// ---- single-block exclusive scan: deg -> rowptr[N+1], cursor copy ----
__global__ void k_scan(const int* __restrict__ deg, int* __restrict__ rowptr,
                       int* __restrict__ cursor){
  __shared__ int lds[1024];
  __shared__ int carry;
  int t = threadIdx.x;
  if (t==0) carry = 0;
  __syncthreads();
  for (long long base = 0; base < N_; base += 1024){
    long long idx = base + t;
    int v = (idx < N_) ? deg[idx] : 0;
    lds[t] = v;
    __syncthreads();
    for (int off=1; off<1024; off<<=1){
      int add = (t >= off) ? lds[t-off] : 0;
      __syncthreads();
      lds[t] += add;
      __syncthreads();
    }
    if (idx < N_){
      int rp = carry + lds[t] - v;      // exclusive
      rowptr[idx] = rp;
      cursor[idx] = rp;
    }
    __syncthreads();
    if (t==1023) carry += lds[1023];
    __syncthreads();
  }
  if (t==0) rowptr[N_] = carry;
}

// ---- tiny: Ae_l[f][h] = sum_c We_l[f, h*64+c]*a_e_l[h,c]; loop_ale_l[h] ----
// small layout: [0..15]=Ae0, [16..31]=Ae1, [32..35]=loop0, [36..39]=loop1
__global__ void k_small(const float* __restrict__ We0, const float* __restrict__ ae0,
                        const float* __restrict__ We1, const float* __restrict__ ae1,
                        const float* __restrict__ sum_ea, float* __restrict__ small){
  int t = threadIdx.x; // 64
  if (t < 32){
    int l = t>>4, f = (t>>2)&3, h = t&3;
    const float* We = l ? We1 : We0;
    const float* ae = l ? ae1 : ae0;
    float s = 0.f;
    for (int cc=0; cc<64; cc++) s += We[f*256 + h*64 + cc]*ae[h*64+cc];
    small[l*16 + f*4 + h] = s;
  }
  __syncthreads();
  if (t < 8){
    int l = t>>2, h = t&3;
    const float* Ae = small + l*16;
    const float invE = 1.f/(float)E_;
    float s = 0.f;
    for (int f=0; f<4; f++) s += sum_ea[f]*invE*Ae[f*4+h];
    small[32 + l*4 + h] = s;
  }
}

// ---- scatter edges into CSR slots; precompute per-edge al_e for both layers ----
__global__ void k_scatter(const int* __restrict__ ei, const float* __restrict__ ea,
                          int* __restrict__ cursor, int* __restrict__ csr_src,
                          float* __restrict__ ale0, float* __restrict__ ale1,
                          const float* __restrict__ small){
  long long e = (long long)blockIdx.x*256 + threadIdx.x;
  if (e >= E_) return;
  int s = ei[e], d = ei[E_+e];
  int pos = atomicAdd(&cursor[d], 1);
  csr_src[pos] = s;
  float e0=ea[e*4+0], e1=ea[e*4+1], e2=ea[e*4+2], e3=ea[e*4+3];
  #pragma unroll
  for (int h=0; h<4; h++){
    ale0[(long long)pos*4+h] = e0*small[0+h]  + e1*small[4+h]  + e2*small[8+h]  + e3*small[12+h];
    ale1[(long long)pos*4+h] = e0*small[16+h] + e1*small[20+h] + e2*small[24+h] + e3*small[28+h];
  }
}

// ---- h0 = x @ W0 (K=5) + al_s0/al_d0 epilogue; one wave per node ----
__global__ void k_h0(const float* __restrict__ x, const float* __restrict__ W0,
                     const float* __restrict__ as0, const float* __restrict__ ad0,
                     float* __restrict__ h0, float* __restrict__ als, float* __restrict__ ald){
  long long wid = ((long long)blockIdx.x*blockDim.x + threadIdx.x) >> 6;
  int lane = threadIdx.x & 63;
  if (wid >= N_) return;
  const float* xr = x + wid*5;
  float xv[5];
  #pragma unroll
  for (int f=0; f<5; f++) xv[f] = xr[f];
  int c = lane*4;
  float a0=0,a1=0,a2=0,a3=0;
  #pragma unroll
  for (int f=0; f<5; f++){
    const float* wr = W0 + f*256 + c;
    a0 += xv[f]*wr[0]; a1 += xv[f]*wr[1]; a2 += xv[f]*wr[2]; a3 += xv[f]*wr[3];
  }
  *(float4*)(h0 + wid*256 + c) = make_float4(a0,a1,a2,a3);
  int head = lane>>4; int cc = (lane&15)*4;
  const float* asp = as0 + head*64 + cc;
  const float* adp = ad0 + head*64 + cc;
  float ss = a0*asp[0]+a1*asp[1]+a2*asp[2]+a3*asp[3];
  float dd = a0*adp[0]+a1*adp[1]+a2*adp[2]+a3*adp[3];
  #pragma unroll
  for (int m=1; m<16; m<<=1){ ss += __shfl_xor(ss, m); dd += __shfl_xor(dd, m); }
  if ((lane&15)==0){ als[wid*4+head]=ss; ald[wid*4+head]=dd; }
}

// ---- GAT aggregation: one wave per dst node, branchless online softmax ----
__global__ void k_agg(const float* __restrict__ hin, const float* __restrict__ als,
                      const float* __restrict__ ald, const int* __restrict__ rowptr,
                      const int* __restrict__ csr_src, const float* __restrict__ ale,
                      const float* __restrict__ small, int loop_off,
                      const float* __restrict__ bias, float* __restrict__ out, int do_relu){
  long long wid = ((long long)blockIdx.x*blockDim.x + threadIdx.x) >> 6;
  int lane = threadIdx.x & 63;
  if (wid >= N_) return;
  int head = lane>>4; int c = lane*4;
  float aldv = ald[wid*4+head];
  float a0 = lrelu(als[wid*4+head] + aldv + small[loop_off+head]);
  float m = a0, d = 1.f;
  float4 hv0 = *(const float4*)(hin + wid*256 + c);   // self-loop message, weight exp(0)=1
  float accx = hv0.x, accy = hv0.y, accz = hv0.z, accw = hv0.w;
  int beg = rowptr[wid], end = rowptr[wid+1];
  for (int i=beg; i<end; i++){
    int s = csr_src[i];
    float a = lrelu(als[(long long)s*4+head] + aldv + ale[(long long)i*4+head]);
    float4 hv = *(const float4*)(hin + (long long)s*256 + c);
    float nm = fmaxf(m, a);
    float sc = __expf(m - nm);
    float p  = __expf(a - nm);
    d = d*sc + p;
    accx = accx*sc + p*hv.x;
    accy = accy*sc + p*hv.y;
    accz = accz*sc + p*hv.z;
    accw = accw*sc + p*hv.w;
    m = nm;
  }
  float inv = 1.f/(d + 1e-16f);
  const float* bp = bias + c;
  float ox = accx*inv + bp[0], oy = accy*inv + bp[1];
  float oz = accz*inv + bp[2], ow = accw*inv + bp[3];
  if (do_relu){ ox=fmaxf(ox,0.f); oy=fmaxf(oy,0.f); oz=fmaxf(oz,0.f); ow=fmaxf(ow,0.f); }
  *(float4*)(out + wid*256 + c) = make_float4(ox,oy,oz,ow);
}

// ---- h1 = x1 @ W1 (fp32, LDS-tiled 64x256) + fused al_s1/al_d1 epilogue ----
__global__ __launch_bounds__(256) void k_gemm(const float* __restrict__ A, const float* __restrict__ B,
                       float* __restrict__ C,
                       const float* __restrict__ as1, const float* __restrict__ ad1,
                       float* __restrict__ als, float* __restrict__ ald){
  __shared__ float xs[64*256];   // 64 KB, row-major [r][f]
  int t = threadIdx.x;
  long long base = (long long)blockIdx.x*64;
  for (int i=t; i<64*64; i+=256){
    int r = i>>6, q = i&63;
    float4 v = make_float4(0,0,0,0);
    long long n = base + r;
    if (n < N_) v = *(const float4*)(A + n*256 + q*4);
    *(float4*)(xs + r*256 + q*4) = v;
  }
  __syncthreads();
  int c = (t&63)*4; int rg = t>>6;   // rg is wave-uniform
  float accx[16], accy[16], accz[16], accw[16];
  #pragma unroll
  for (int r=0;r<16;r++){accx[r]=0;accy[r]=0;accz[r]=0;accw[r]=0;}
  const float* Bp = B + c;
  for (int f=0; f<256; f+=4){
    float4 w0 = *(const float4*)(Bp + (f+0)*256);
    float4 w1 = *(const float4*)(Bp + (f+1)*256);
    float4 w2 = *(const float4*)(Bp + (f+2)*256);
    float4 w3 = *(const float4*)(Bp + (f+3)*256);
    #pragma unroll
    for (int r=0;r<16;r++){
      float4 xv = *(const float4*)(xs + (rg*16+r)*256 + f);  // broadcast b128
      accx[r] += xv.x*w0.x + xv.y*w1.x + xv.z*w2.x + xv.w*w3.x;
      accy[r] += xv.x*w0.y + xv.y*w1.y + xv.z*w2.y + xv.w*w3.y;
      accz[r] += xv.x*w0.z + xv.y*w1.z + xv.z*w2.z + xv.w*w3.z;
      accw[r] += xv.x*w0.w + xv.y*w1.w + xv.z*w2.w + xv.w*w3.w;
    }
  }
  int lane = t&63; int head = lane>>4; int cc = (lane&15)*4;
  float4 asv = *(const float4*)(as1 + head*64 + cc);
  float4 adv = *(const float4*)(ad1 + head*64 + cc);
  #pragma unroll
  for (int r=0;r<16;r++){
    long long n = base + rg*16 + r;    // wave-uniform
    if (n < N_){
      *(float4*)(C + n*256 + c) = make_float4(accx[r],accy[r],accz[r],accw[r]);
      float ss = accx[r]*asv.x + accy[r]*asv.y + accz[r]*asv.z + accw[r]*asv.w;
      float dd = accx[r]*adv.x + accy[r]*adv.y + accz[r]*adv.z + accw[r]*adv.w;
      #pragma unroll
      for (int mm=1; mm<16; mm<<=1){ ss += __shfl_xor(ss, mm); dd += __shfl_xor(dd, mm); }
      if ((lane&15)==0){ als[n*4+head]=ss; ald[n*4+head]=dd; }
    }
  }
}

// ---- column-wise sum & max over nodes ----
__global__ void k_pool1(const float* __restrict__ h2, float* __restrict__ sum_pool,
                        unsigned* __restrict__ maxkey){
  int c = threadIdx.x; // 256
  float s = 0.f; float m = -3.4e38f;
  for (long long n = blockIdx.x; n < N_; n += gridDim.x){
    float v = h2[n*256+c]; s += v; m = fmaxf(m, v);
  }
  atomicAdd(&sum_pool[c], s);
  atomicMax(&maxkey[c], fkey(m));
}

// ---- s[n] = dot(h2[n], mean_pool); track global max ----
__global__ void k_atts(const float* __restrict__ h2, const float* __restrict__ sum_pool,
                       float* __restrict__ sarr, unsigned* __restrict__ smax){
  __shared__ float lmax[4];
  int t = threadIdx.x; int lane = t&63; int w = t>>6;
  const float invN = 1.f/(float)N_;
  int c = lane*4;
  float4 mp = *(const float4*)(sum_pool + c);
  float mymax = -3.4e38f;
  for (long long wid = (long long)blockIdx.x*4 + w; wid < N_; wid += (long long)gridDim.x*4){
    float4 hv = *(const float4*)(h2 + wid*256 + c);
    float s = (hv.x*mp.x + hv.y*mp.y + hv.z*mp.z + hv.w*mp.w)*invN;
    #pragma unroll
    for (int m=1; m<64; m<<=1) s += __shfl_xor(s, m);
    if (lane==0) sarr[wid] = s;
    mymax = fmaxf(mymax, s);
  }
  if (lane==0) lmax[w] = mymax;
  __syncthreads();
  if (t==0){
    float mm = fmaxf(fmaxf(lmax[0],lmax[1]), fmaxf(lmax[2],lmax[3]));
    atomicMax(smax, fkey(mm));
  }
}

// ---- sum of exp(s - smax) ----
__global__ void k_attd(const float* __restrict__ sarr, const unsigned* __restrict__ smax,
                       float* __restrict__ ssum){
  __shared__ float lds[256];
  int t = threadIdx.x;
  float mx = unfkey(*smax);
  float s = 0.f;
  for (long long i = (long long)blockIdx.x*256 + t; i < N_; i += (long long)gridDim.x*256)
    s += __expf(sarr[i] - mx);
  lds[t] = s; __syncthreads();
  for (int st=128; st>=1; st>>=1){ if (t<st) lds[t]+=lds[t+st]; __syncthreads(); }
  if (t==0) atomicAdd(ssum, lds[0]);
}

// ---- att_pool[c] = sum_n h2[n][c]*softmax(s)[n] ----
__global__ void k_attp(const float* __restrict__ h2, const float* __restrict__ sarr,
                       const unsigned* __restrict__ smax, const float* __restrict__ ssum,
                       float* __restrict__ att_pool){
  int c = threadIdx.x; // 256
  float mx = unfkey(*smax);
  float inv = 1.f/(*ssum);
  float acc = 0.f;
  for (long long n = blockIdx.x; n < N_; n += gridDim.x){
    float w = __expf(sarr[n]-mx)*inv;
    acc += h2[n*256+c]*w;
  }
  atomicAdd(&att_pool[c], acc);
}

// ---- final MLP: [768] -> 128 -> 64 -> 128 ----
__global__ void k_mlp(const float* __restrict__ sum_pool, const unsigned* __restrict__ maxkey,
                      const float* __restrict__ att_pool,
                      const float* __restrict__ Wm1, const float* __restrict__ bm1,
                      const float* __restrict__ Wm2, const float* __restrict__ bm2,
                      const float* __restrict__ Wm3, const float* __restrict__ bm3,
                      float* __restrict__ out){
  __shared__ float comb[768]; __shared__ float z1[128]; __shared__ float z2[64];
  int t = threadIdx.x; // 256
  const float invN = 1.f/(float)N_;
  comb[t]       = sum_pool[t]*invN;
  comb[256+t]   = unfkey(maxkey[t]);
  comb[512+t]   = att_pool[t];
  __syncthreads();
  if (t < 128){
    float a = bm1[t];
    for (int f=0; f<768; f++) a += comb[f]*Wm1[f*128+t];
    z1[t] = fmaxf(a, 0.f);
  }
  __syncthreads();
  if (t < 64){
    float a = bm2[t];
    for (int f=0; f<128; f++) a += z1[f]*Wm2[f*64+t];
    z2[t] = fmaxf(a, 0.f);
  }
  __syncthreads();
  if (t < 128){
    float a = bm3[t];
    for (int f=0; f<64; f++) a += z2[f]*Wm3[f*128+t];
    out[t] = a;
  }
}

extern "C" void kernel_launch(void* const* d_in, const int* in_sizes, int n_in,
                              void* d_out, int out_size, void* d_ws, size_t ws_size,
                              hipStream_t stream){
  (void)in_sizes; (void)n_in; (void)out_size; (void)ws_size;
  const float* x   = (const float*)d_in[0];
  const int*   ei  = (const int*)d_in[1];
  const float* ea  = (const float*)d_in[2];
  const float* W0  = (const float*)d_in[3];
  const float* as0 = (const float*)d_in[4];
  const float* ad0 = (const float*)d_in[5];
  const float* We0 = (const float*)d_in[6];
  const float* ae0 = (const float*)d_in[7];
  const float* b0  = (const float*)d_in[8];
  const float* W1  = (const float*)d_in[9];
  const float* as1 = (const float*)d_in[10];
  const float* ad1 = (const float*)d_in[11];
  const float* We1 = (const float*)d_in[12];
  const float* ae1 = (const float*)d_in[13];
  const float* b1  = (const float*)d_in[14];
  const float* Wm1 = (const float*)d_in[15];
  const float* bm1 = (const float*)d_in[16];
  const float* Wm2 = (const float*)d_in[17];
  const float* bm2 = (const float*)d_in[18];
  const float* Wm3 = (const float*)d_in[19];
  const float* bm3 = (const float*)d_in[20];
  float* out = (float*)d_out;

  char* ws = (char*)d_ws;
  size_t o = 0;
  auto alloc = [&](size_t bytes)->size_t{
    size_t r = o; o = (o + bytes + 255) & ~(size_t)255; return r;
  };
  size_t o_bufA   = alloc((size_t)N_*256*4);   // h0, then h1
  size_t o_bufB   = alloc((size_t)N_*256*4);   // x1, then h2
  size_t o_als0   = alloc((size_t)N_*4*4);
  size_t o_ald0   = alloc((size_t)N_*4*4);
  size_t o_als1   = alloc((size_t)N_*4*4);
  size_t o_ald1   = alloc((size_t)N_*4*4);
  size_t o_rowptr = alloc((size_t)(N_+1)*4);
  size_t o_cursor = alloc((size_t)N_*4);
  size_t o_csrsrc = alloc((size_t)E_*4);
  size_t o_ale0   = alloc((size_t)E_*4*4);
  size_t o_ale1   = alloc((size_t)E_*4*4);
  size_t o_sarr   = alloc((size_t)N_*4);
  // --- zero block ---
  size_t zstart   = o;
  size_t o_deg    = alloc((size_t)N_*4);
  size_t o_sumea  = alloc(16);
  size_t o_sumpool= alloc(256*4);
  size_t o_maxkey = alloc(256*4);
  size_t o_attpool= alloc(256*4);
  size_t o_smax   = alloc(4);
  size_t o_ssum   = alloc(4);
  size_t zend     = o;
  // --- non-zero small block ---
  size_t o_small  = alloc(40*4);

  float* bufA   = (float*)(ws + o_bufA);
  float* bufB   = (float*)(ws + o_bufB);
  float* pals0  = (float*)(ws + o_als0);
  float* pald0  = (float*)(ws + o_ald0);
  float* pals1  = (float*)(ws + o_als1);
  float* pald1  = (float*)(ws + o_ald1);
  int*   rowptr = (int*)(ws + o_rowptr);
  int*   cursor = (int*)(ws + o_cursor);
  int*   csrsrc = (int*)(ws + o_csrsrc);
  float* ale0   = (float*)(ws + o_ale0);
  float* ale1   = (float*)(ws + o_ale1);
  float* sarr   = (float*)(ws + o_sarr);
  int*   deg    = (int*)(ws + o_deg);
  float* sumea  = (float*)(ws + o_sumea);
  float* sumpool= (float*)(ws + o_sumpool);
  unsigned* maxkey = (unsigned*)(ws + o_maxkey);
  float* attpool= (float*)(ws + o_attpool);
  unsigned* smax= (unsigned*)(ws + o_smax);
  float* ssum   = (float*)(ws + o_ssum);
  float* small  = (float*)(ws + o_small);

  hipMemsetAsync(ws + zstart, 0, zend - zstart, stream);

  int eb = (int)((E_ + 255)/256);          // 3125
  int nb_wave = (int)((N_*64 + 255)/256);  // 12500 (one wave per node)

  k_sumea  <<<1024, 256, 0, stream>>>(ea, sumea);
  k_deg    <<<eb, 256, 0, stream>>>(ei, deg);
  k_scan   <<<1, 1024, 0, stream>>>(deg, rowptr, cursor);
  k_small  <<<1, 64, 0, stream>>>(We0, ae0, We1, ae1, sumea, small);
  k_scatter<<<eb, 256, 0, stream>>>(ei, ea, cursor, csrsrc, ale0, ale1, small);
  k_h0     <<<nb_wave, 256, 0, stream>>>(x, W0, as0, ad0, bufA, pals0, pald0);
  k_agg    <<<nb_wave, 256, 0, stream>>>(bufA, pals0, pald0, rowptr, csrsrc, ale0,
                                         small, 32, b0, bufB, 1);
  k_gemm   <<<(int)((N_+63)/64), 256, 0, stream>>>(bufB, W1, bufA, as1, ad1, pals1, pald1);
  k_agg    <<<nb_wave, 256, 0, stream>>>(bufA, pals1, pald1, rowptr, csrsrc, ale1,
                                         small, 36, b1, bufB, 0);
  k_pool1  <<<256, 256, 0, stream>>>(bufB, sumpool, maxkey);
  k_atts   <<<1024, 256, 0, stream>>>(bufB, sumpool, sarr, smax);
  k_attd   <<<128, 256, 0, stream>>>(sarr, smax, ssum);
  k_attp   <<<256, 256, 0, stream>>>(bufB, sarr, smax, ssum, attpool);
  k_mlp    <<<1, 256, 0, stream>>>(sumpool, maxkey, attpool,
                                   Wm1, bm1, Wm2, bm2, Wm3, bm3, out);
}

// Round 2
// 759.469 us; speedup vs baseline: 1.1459x; 1.1459x over previous
//
#include <hip/hip_runtime.h>
#include <hip/hip_fp16.h>

static const long long N_ = 50000;
static const long long E_ = 800000;

typedef __attribute__((ext_vector_type(8))) short bf16x8;
typedef __attribute__((ext_vector_type(4))) float f32x4;

__device__ __forceinline__ float lrelu(float x){ return x >= 0.f ? x : 0.2f*x; }
__device__ __forceinline__ unsigned fkey(float x){
  unsigned u = __float_as_uint(x);
  return (u & 0x80000000u) ? ~u : (u | 0x80000000u);
}
__device__ __forceinline__ float unfkey(unsigned k){
  return __uint_as_float((k & 0x80000000u) ? (k & 0x7fffffffu) : ~k);
}

// ---- column sums of edge_attr [E,4] -> sum_ea[4] ----
__global__ void k_sumea(const float* __restrict__ ea, float* __restrict__ sum_ea){
  __shared__ float lds[256];
  int t = threadIdx.x;
  long long total = E_*4;
  float s = 0.f;
  for (long long i = (long long)blockIdx.x*256 + t; i < total; i += (long long)gridDim.x*256)
    s += ea[i];                          // col = i&3 == t&3 (strides are %4==0)
  lds[t] = s; __syncthreads();
  for (int st=128; st>=4; st>>=1){ if (t<st) lds[t] += lds[t+st]; __syncthreads(); }
  if (t<4) atomicAdd(&sum_ea[t], lds[t]);
}

// ---- in-degree histogram over dst ----
__global__ void k_deg(const int* __restrict__ ei, int* __restrict__ deg){
  long long e = (long long)blockIdx.x*256 + threadIdx.x;
  if (e < E_) atomicAdd(&deg[ei[E_ + e]], 1);
}

// ---- single-block scan, thread-sequential chunks (20 barriers total) ----
__global__ void k_scan(const int* __restrict__ deg, int* __restrict__ rowptr,
                       int* __restrict__ cursor){
  __shared__ int ts[1024];
  int t = threadIdx.x;
  const int CH = 49;   // 1024*49 = 50176 >= N_
  long long s0 = (long long)t*CH;
  int s = 0;
  for (int i=0;i<CH;i++){ long long idx = s0+i; if (idx < N_) s += deg[idx]; }
  ts[t] = s; __syncthreads();
  for (int off=1; off<1024; off<<=1){
    int add = (t >= off) ? ts[t-off] : 0;
    __syncthreads();
    ts[t] += add;
    __syncthreads();
  }
  int run = (t > 0) ? ts[t-1] : 0;   // exclusive prefix at chunk start
  for (int i=0;i<CH;i++){
    long long idx = s0+i;
    if (idx < N_){ rowptr[idx] = run; cursor[idx] = run; run += deg[idx]; }
  }
  if (t==1023) rowptr[N_] = ts[1023];
}

// ---- tiny: Ae_l[f][h]; loop_ale_l[h] ----
// small layout: [0..15]=Ae0, [16..31]=Ae1, [32..35]=loop0, [36..39]=loop1
__global__ void k_small(const float* __restrict__ We0, const float* __restrict__ ae0,
                        const float* __restrict__ We1, const float* __restrict__ ae1,
                        const float* __restrict__ sum_ea, float* __restrict__ small){
  int t = threadIdx.x; // 64
  if (t < 32){
    int l = t>>4, f = (t>>2)&3, h = t&3;
    const float* We = l ? We1 : We0;
    const float* ae = l ? ae1 : ae0;
    float s = 0.f;
    for (int cc=0; cc<64; cc++) s += We[f*256 + h*64 + cc]*ae[h*64+cc];
    small[l*16 + f*4 + h] = s;
  }
  __syncthreads();
  if (t < 8){
    int l = t>>2, h = t&3;
    const float* Ae = small + l*16;
    const float invE = 1.f/(float)E_;
    float s = 0.f;
    for (int f=0; f<4; f++) s += sum_ea[f]*invE*Ae[f*4+h];
    small[32 + l*4 + h] = s;
  }
}

// ---- scatter edges into CSR slots; precompute per-edge al_e for both layers ----
__global__ void k_scatter(const int* __restrict__ ei, const float* __restrict__ ea,
                          int* __restrict__ cursor, int* __restrict__ csr_src,
                          float* __restrict__ ale0, float* __restrict__ ale1,
                          const float* __restrict__ small){
  long long e = (long long)blockIdx.x*256 + threadIdx.x;
  if (e >= E_) return;
  int s = ei[e], d = ei[E_+e];
  int pos = atomicAdd(&cursor[d], 1);
  csr_src[pos] = s;
  float e0=ea[e*4+0], e1=ea[e*4+1], e2=ea[e*4+2], e3=ea[e*4+3];
  #pragma unroll
  for (int h=0; h<4; h++){
    ale0[(long long)pos*4+h] = e0*small[0+h]  + e1*small[4+h]  + e2*small[8+h]  + e3*small[12+h];
    ale1[(long long)pos*4+h] = e0*small[16+h] + e1*small[20+h] + e2*small[24+h] + e3*small[28+h];
  }
}

// ---- h0 = x @ W0 (K=5), stored fp16; als0/ald0 from fp32 pre-round values ----
__global__ void k_h0(const float* __restrict__ x, const float* __restrict__ W0,
                     const float* __restrict__ as0, const float* __restrict__ ad0,
                     __half* __restrict__ h0, float* __restrict__ als, float* __restrict__ ald){
  long long wid = ((long long)blockIdx.x*blockDim.x + threadIdx.x) >> 6;
  int lane = threadIdx.x & 63;
  if (wid >= N_) return;
  const float* xr = x + wid*5;
  float xv[5];
  #pragma unroll
  for (int f=0; f<5; f++) xv[f] = xr[f];
  int c = lane*4;
  float a0=0,a1=0,a2=0,a3=0;
  #pragma unroll
  for (int f=0; f<5; f++){
    const float* wr = W0 + f*256 + c;
    a0 += xv[f]*wr[0]; a1 += xv[f]*wr[1]; a2 += xv[f]*wr[2]; a3 += xv[f]*wr[3];
  }
  __half2 p01 = __floats2half2_rn(a0,a1);
  __half2 p23 = __floats2half2_rn(a2,a3);
  uint2 pk = make_uint2(*(unsigned*)&p01, *(unsigned*)&p23);
  *(uint2*)(h0 + wid*256 + c) = pk;
  const float* asp = as0 + c;
  const float* adp = ad0 + c;
  float ss = a0*asp[0]+a1*asp[1]+a2*asp[2]+a3*asp[3];
  float dd = a0*adp[0]+a1*adp[1]+a2*adp[2]+a3*adp[3];
  int head = lane>>4;
  #pragma unroll
  for (int m=1; m<16; m<<=1){ ss += __shfl_xor(ss, m); dd += __shfl_xor(dd, m); }
  if ((lane&15)==0){ als[wid*4+head]=ss; ald[wid*4+head]=dd; }
}

// ---- GAT aggregation: one wave per dst node; fp16 h gather, fp32 output ----
__global__ void k_agg(const __half* __restrict__ hin, const float* __restrict__ als,
                      const float* __restrict__ ald, const int* __restrict__ rowptr,
                      const int* __restrict__ csr_src, const float* __restrict__ ale,
                      const float* __restrict__ small, int loop_off,
                      const float* __restrict__ bias, float* __restrict__ out, int do_relu){
  long long wid = ((long long)blockIdx.x*blockDim.x + threadIdx.x) >> 6;
  int lane = threadIdx.x & 63;
  if (wid >= N_) return;
  int head = lane>>4; int c = lane*4;
  float aldv = ald[wid*4+head];
  float a0 = lrelu(als[wid*4+head] + aldv + small[loop_off+head]);
  float m = a0, d = 1.f;
  uint2 pk0 = *(const uint2*)(hin + wid*256 + c);   // self-loop message, weight exp(0)=1
  float2 f01 = __half22float2(*(__half2*)&pk0.x);
  float2 f23 = __half22float2(*(__half2*)&pk0.y);
  float accx = f01.x, accy = f01.y, accz = f23.x, accw = f23.y;
  int beg = rowptr[wid], end = rowptr[wid+1];
  for (int i=beg; i<end; i++){
    int s = csr_src[i];
    float a = lrelu(als[(long long)s*4+head] + aldv + ale[(long long)i*4+head]);
    uint2 pk = *(const uint2*)(hin + (long long)s*256 + c);
    float2 g01 = __half22float2(*(__half2*)&pk.x);
    float2 g23 = __half22float2(*(__half2*)&pk.y);
    float nm = fmaxf(m, a);
    float sc = __expf(m - nm);
    float p  = __expf(a - nm);
    d = d*sc + p;
    accx = accx*sc + p*g01.x;
    accy = accy*sc + p*g01.y;
    accz = accz*sc + p*g23.x;
    accw = accw*sc + p*g23.y;
    m = nm;
  }
  float inv = 1.f/(d + 1e-16f);
  const float* bp = bias + c;
  float ox = accx*inv + bp[0], oy = accy*inv + bp[1];
  float oz = accz*inv + bp[2], ow = accw*inv + bp[3];
  if (do_relu){ ox=fmaxf(ox,0.f); oy=fmaxf(oy,0.f); oz=fmaxf(oz,0.f); ow=fmaxf(ow,0.f); }
  *(float4*)(out + wid*256 + c) = make_float4(ox,oy,oz,ow);
}

// ---- prep: W1 -> hi/lo bf16 in MFMA B-fragment layout ----
// B[k][n]: tile t=n>>4, kb=k>>5, lane=((k>>3)&3)*16+(n&15), j=k&7
__global__ void k_prepB(const float* __restrict__ W1, ushort* __restrict__ Bhi,
                        ushort* __restrict__ Blo){
  int k = blockIdx.x;     // 256
  int n = threadIdx.x;    // 256
  float v = W1[k*256+n];
  unsigned u = __float_as_uint(v);
  ushort hi = (ushort)(u>>16);
  float rem = v - __uint_as_float(u & 0xffff0000u);
  unsigned ur = __float_as_uint(rem);
  ushort lo = (ushort)((ur + 0x7fff + ((ur>>16)&1)) >> 16);
  int t = n>>4, kb = k>>5, q = (k>>3)&3, j = k&7;
  long long idx = ((((long long)t*8+kb)*64 + q*16 + (n&15))<<3) + j;
  Bhi[idx] = hi; Blo[idx] = lo;
}

// ---- h1 = x1 @ W1 via split-bf16 MFMA (3 products); fp16 out; fused als1/ald1 ----
// block: 256 thr = 4 waves; M-tile 32 rows. wave w: rows (w>>1)*16.., cols (w&1)*128..
__global__ __launch_bounds__(256) void k_gemm(const float* __restrict__ A,
    const ushort* __restrict__ Bhi, const ushort* __restrict__ Blo,
    __half* __restrict__ Ch, const float* __restrict__ as1, const float* __restrict__ ad1,
    float* __restrict__ als, float* __restrict__ ald){
  __shared__ ushort Ah[32*264];   // +8 pad: row stride 528B -> 2-way (free) on b128 reads
  __shared__ ushort Al[32*264];
  int t = threadIdx.x;
  long long base = (long long)blockIdx.x*32;
  for (int i=t; i<2048; i+=256){
    int r = i>>6, q4 = i&63;
    float4 v = make_float4(0.f,0.f,0.f,0.f);
    if (base + r < N_) v = *(const float4*)(A + (base+r)*256 + q4*4);
    float vv[4] = {v.x,v.y,v.z,v.w};
    ushort hh[4], ll[4];
    #pragma unroll
    for (int e=0;e<4;e++){
      unsigned u = __float_as_uint(vv[e]);
      hh[e] = (ushort)(u>>16);                             // hi = truncate
      float rem = vv[e] - __uint_as_float(u & 0xffff0000u); // exact
      unsigned ur = __float_as_uint(rem);
      ll[e] = (ushort)((ur + 0x7fff + ((ur>>16)&1)) >> 16); // lo = RN
    }
    int off = r*264 + q4*4;
    *(ushort4*)(Ah+off) = make_ushort4(hh[0],hh[1],hh[2],hh[3]);
    *(ushort4*)(Al+off) = make_ushort4(ll[0],ll[1],ll[2],ll[3]);
  }
  __syncthreads();
  int w = t>>6, lane = t&63, m = lane&15, q = lane>>4;
  int rbase = (w>>1)*16;
  int nhalf = (w&1)*8;
  f32x4 acc[8];
  #pragma unroll
  for (int i=0;i<8;i++) acc[i] = (f32x4){0.f,0.f,0.f,0.f};
  for (int kb=0; kb<8; kb++){
    int aoff = (rbase+m)*264 + kb*32 + q*8;
    bf16x8 ah = *(const bf16x8*)(Ah + aoff);
    bf16x8 al = *(const bf16x8*)(Al + aoff);
    #pragma unroll
    for (int tt=0; tt<8; tt++){
      long long bidx = ((((long long)(nhalf+tt)*8+kb)*64 + lane)<<3);
      bf16x8 bh = *(const bf16x8*)(Bhi + bidx);
      bf16x8 bl = *(const bf16x8*)(Blo + bidx);
      acc[tt] = __builtin_amdgcn_mfma_f32_16x16x32_bf16(ah, bh, acc[tt], 0,0,0);
      acc[tt] = __builtin_amdgcn_mfma_f32_16x16x32_bf16(al, bh, acc[tt], 0,0,0);
      acc[tt] = __builtin_amdgcn_mfma_f32_16x16x32_bf16(ah, bl, acc[tt], 0,0,0);
    }
  }
  // fused al_s1/al_d1: wave covers 2 heads (w&1 -> heads 0,1 or 2,3)
  float ssv[4][2], ddv[4][2];
  #pragma unroll
  for (int r=0;r<4;r++){ ssv[r][0]=0.f; ssv[r][1]=0.f; ddv[r][0]=0.f; ddv[r][1]=0.f; }
  #pragma unroll
  for (int tt=0; tt<8; tt++){
    int col = (nhalf+tt)*16 + m;
    float as_ = as1[col], ad_ = ad1[col];
    int hh = tt>>2;
    #pragma unroll
    for (int r=0;r<4;r++){
      ssv[r][hh] += acc[tt][r]*as_;
      ddv[r][hh] += acc[tt][r]*ad_;
    }
  }
  #pragma unroll
  for (int r=0;r<4;r++){
    #pragma unroll
    for (int hh=0; hh<2; hh++){
      #pragma unroll
      for (int mm=1; mm<16; mm<<=1){
        ssv[r][hh] += __shfl_xor(ssv[r][hh], mm);
        ddv[r][hh] += __shfl_xor(ddv[r][hh], mm);
      }
    }
  }
  #pragma unroll
  for (int r=0;r<4;r++){
    long long grow = base + rbase + q*4 + r;
    if (grow < N_){
      #pragma unroll
      for (int tt=0; tt<8; tt++)
        Ch[grow*256 + (nhalf+tt)*16 + m] = __float2half(acc[tt][r]);
      if (m==0){
        int hb = (w&1)*2;
        als[grow*4 + hb+0] = ssv[r][0];
        ald[grow*4 + hb+0] = ddv[r][0];
        als[grow*4 + hb+1] = ssv[r][1];
        ald[grow*4 + hb+1] = ddv[r][1];
      }
    }
  }
}

// ---- column-wise sum & max over nodes ----
__global__ void k_pool1(const float* __restrict__ h2, float* __restrict__ sum_pool,
                        unsigned* __restrict__ maxkey){
  int c = threadIdx.x; // 256
  float s = 0.f; float m = -3.4e38f;
  for (long long n = blockIdx.x; n < N_; n += gridDim.x){
    float v = h2[n*256+c]; s += v; m = fmaxf(m, v);
  }
  atomicAdd(&sum_pool[c], s);
  atomicMax(&maxkey[c], fkey(m));
}

// ---- s[n] = dot(h2[n], mean_pool); track global max ----
__global__ void k_atts(const float* __restrict__ h2, const float* __restrict__ sum_pool,
                       float* __restrict__ sarr, unsigned* __restrict__ smax){
  __shared__ float lmax[4];
  int t = threadIdx.x; int lane = t&63; int w = t>>6;
  const float invN = 1.f/(float)N_;
  int c = lane*4;
  float4 mp = *(const float4*)(sum_pool + c);
  float mymax = -3.4e38f;
  for (long long wid = (long long)blockIdx.x*4 + w; wid < N_; wid += (long long)gridDim.x*4){
    float4 hv = *(const float4*)(h2 + wid*256 + c);
    float s = (hv.x*mp.x + hv.y*mp.y + hv.z*mp.z + hv.w*mp.w)*invN;
    #pragma unroll
    for (int m=1; m<64; m<<=1) s += __shfl_xor(s, m);
    if (lane==0) sarr[wid] = s;
    mymax = fmaxf(mymax, s);
  }
  if (lane==0) lmax[w] = mymax;
  __syncthreads();
  if (t==0){
    float mm = fmaxf(fmaxf(lmax[0],lmax[1]), fmaxf(lmax[2],lmax[3]));
    atomicMax(smax, fkey(mm));
  }
}

// ---- sum of exp(s - smax) ----
__global__ void k_attd(const float* __restrict__ sarr, const unsigned* __restrict__ smax,
                       float* __restrict__ ssum){
  __shared__ float lds[256];
  int t = threadIdx.x;
  float mx = unfkey(*smax);
  float s = 0.f;
  for (long long i = (long long)blockIdx.x*256 + t; i < N_; i += (long long)gridDim.x*256)
    s += __expf(sarr[i] - mx);
  lds[t] = s; __syncthreads();
  for (int st=128; st>=1; st>>=1){ if (t<st) lds[t]+=lds[t+st]; __syncthreads(); }
  if (t==0) atomicAdd(ssum, lds[0]);
}

// ---- att_pool[c] = sum_n h2[n][c]*softmax(s)[n] ----
__global__ void k_attp(const float* __restrict__ h2, const float* __restrict__ sarr,
                       const unsigned* __restrict__ smax, const float* __restrict__ ssum,
                       float* __restrict__ att_pool){
  int c = threadIdx.x; // 256
  float mx = unfkey(*smax);
  float inv = 1.f/(*ssum);
  float acc = 0.f;
  for (long long n = blockIdx.x; n < N_; n += gridDim.x){
    float w = __expf(sarr[n]-mx)*inv;
    acc += h2[n*256+c]*w;
  }
  atomicAdd(&att_pool[c], acc);
}

// ---- final MLP: [768] -> 128 -> 64 -> 128 ----
__global__ void k_mlp(const float* __restrict__ sum_pool, const unsigned* __restrict__ maxkey,
                      const float* __restrict__ att_pool,
                      const float* __restrict__ Wm1, const float* __restrict__ bm1,
                      const float* __restrict__ Wm2, const float* __restrict__ bm2,
                      const float* __restrict__ Wm3, const float* __restrict__ bm3,
                      float* __restrict__ out){
  __shared__ float comb[768]; __shared__ float z1[128]; __shared__ float z2[64];
  int t = threadIdx.x; // 256
  const float invN = 1.f/(float)N_;
  comb[t]       = sum_pool[t]*invN;
  comb[256+t]   = unfkey(maxkey[t]);
  comb[512+t]   = att_pool[t];
  __syncthreads();
  if (t < 128){
    float a = bm1[t];
    for (int f=0; f<768; f++) a += comb[f]*Wm1[f*128+t];
    z1[t] = fmaxf(a, 0.f);
  }
  __syncthreads();
  if (t < 64){
    float a = bm2[t];
    for (int f=0; f<128; f++) a += z1[f]*Wm2[f*64+t];
    z2[t] = fmaxf(a, 0.f);
  }
  __syncthreads();
  if (t < 128){
    float a = bm3[t];
    for (int f=0; f<64; f++) a += z2[f]*Wm3[f*128+t];
    out[t] = a;
  }
}

extern "C" void kernel_launch(void* const* d_in, const int* in_sizes, int n_in,
                              void* d_out, int out_size, void* d_ws, size_t ws_size,
                              hipStream_t stream){
  (void)in_sizes; (void)n_in; (void)out_size; (void)ws_size;
  const float* x   = (const float*)d_in[0];
  const int*   ei  = (const int*)d_in[1];
  const float* ea  = (const float*)d_in[2];
  const float* W0  = (const float*)d_in[3];
  const float* as0 = (const float*)d_in[4];
  const float* ad0 = (const float*)d_in[5];
  const float* We0 = (const float*)d_in[6];
  const float* ae0 = (const float*)d_in[7];
  const float* b0  = (const float*)d_in[8];
  const float* W1  = (const float*)d_in[9];
  const float* as1 = (const float*)d_in[10];
  const float* ad1 = (const float*)d_in[11];
  const float* We1 = (const float*)d_in[12];
  const float* ae1 = (const float*)d_in[13];
  const float* b1  = (const float*)d_in[14];
  const float* Wm1 = (const float*)d_in[15];
  const float* bm1 = (const float*)d_in[16];
  const float* Wm2 = (const float*)d_in[17];
  const float* bm2 = (const float*)d_in[18];
  const float* Wm3 = (const float*)d_in[19];
  const float* bm3 = (const float*)d_in[20];
  float* out = (float*)d_out;

  char* ws = (char*)d_ws;
  size_t o = 0;
  auto alloc = [&](size_t bytes)->size_t{
    size_t r = o; o = (o + bytes + 255) & ~(size_t)255; return r;
  };
  size_t o_bufF   = alloc((size_t)N_*256*4);   // x1, then h2 (fp32)
  size_t o_bufH   = alloc((size_t)N_*256*2);   // h0, then h1 (fp16)
  size_t o_als0   = alloc((size_t)N_*4*4);
  size_t o_ald0   = alloc((size_t)N_*4*4);
  size_t o_als1   = alloc((size_t)N_*4*4);
  size_t o_ald1   = alloc((size_t)N_*4*4);
  size_t o_rowptr = alloc((size_t)(N_+1)*4);
  size_t o_cursor = alloc((size_t)N_*4);
  size_t o_csrsrc = alloc((size_t)E_*4);
  size_t o_ale0   = alloc((size_t)E_*4*4);
  size_t o_ale1   = alloc((size_t)E_*4*4);
  size_t o_sarr   = alloc((size_t)N_*4);
  size_t o_Bhi    = alloc((size_t)256*256*2);
  size_t o_Blo    = alloc((size_t)256*256*2);
  // --- zero block ---
  size_t zstart   = o;
  size_t o_deg    = alloc((size_t)N_*4);
  size_t o_sumea  = alloc(16);
  size_t o_sumpool= alloc(256*4);
  size_t o_maxkey = alloc(256*4);
  size_t o_attpool= alloc(256*4);
  size_t o_smax   = alloc(4);
  size_t o_ssum   = alloc(4);
  size_t zend     = o;
  size_t o_small  = alloc(40*4);

  float*  bufF   = (float*)(ws + o_bufF);
  __half* bufH   = (__half*)(ws + o_bufH);
  float* pals0  = (float*)(ws + o_als0);
  float* pald0  = (float*)(ws + o_ald0);
  float* pals1  = (float*)(ws + o_als1);
  float* pald1  = (float*)(ws + o_ald1);
  int*   rowptr = (int*)(ws + o_rowptr);
  int*   cursor = (int*)(ws + o_cursor);
  int*   csrsrc = (int*)(ws + o_csrsrc);
  float* ale0   = (float*)(ws + o_ale0);
  float* ale1   = (float*)(ws + o_ale1);
  float* sarr   = (float*)(ws + o_sarr);
  ushort* Bhi   = (ushort*)(ws + o_Bhi);
  ushort* Blo   = (ushort*)(ws + o_Blo);
  int*   deg    = (int*)(ws + o_deg);
  float* sumea  = (float*)(ws + o_sumea);
  float* sumpool= (float*)(ws + o_sumpool);
  unsigned* maxkey = (unsigned*)(ws + o_maxkey);
  float* attpool= (float*)(ws + o_attpool);
  unsigned* smax= (unsigned*)(ws + o_smax);
  float* ssum   = (float*)(ws + o_ssum);
  float* small  = (float*)(ws + o_small);

  hipMemsetAsync(ws + zstart, 0, zend - zstart, stream);

  int eb = (int)((E_ + 255)/256);          // 3125
  int nb_wave = (int)((N_*64 + 255)/256);  // 12500 (one wave per node)
  int gb = (int)((N_ + 31)/32);            // 1563 gemm blocks

  k_sumea  <<<1024, 256, 0, stream>>>(ea, sumea);
  k_deg    <<<eb, 256, 0, stream>>>(ei, deg);
  k_prepB  <<<256, 256, 0, stream>>>(W1, Bhi, Blo);
  k_scan   <<<1, 1024, 0, stream>>>(deg, rowptr, cursor);
  k_small  <<<1, 64, 0, stream>>>(We0, ae0, We1, ae1, sumea, small);
  k_scatter<<<eb, 256, 0, stream>>>(ei, ea, cursor, csrsrc, ale0, ale1, small);
  k_h0     <<<nb_wave, 256, 0, stream>>>(x, W0, as0, ad0, bufH, pals0, pald0);
  k_agg    <<<nb_wave, 256, 0, stream>>>(bufH, pals0, pald0, rowptr, csrsrc, ale0,
                                         small, 32, b0, bufF, 1);      // x1 (fp32)
  k_gemm   <<<gb, 256, 0, stream>>>(bufF, Bhi, Blo, bufH, as1, ad1, pals1, pald1); // h1 (fp16)
  k_agg    <<<nb_wave, 256, 0, stream>>>(bufH, pals1, pald1, rowptr, csrsrc, ale1,
                                         small, 36, b1, bufF, 0);      // h2 (fp32)
  k_pool1  <<<256, 256, 0, stream>>>(bufF, sumpool, maxkey);
  k_atts   <<<1024, 256, 0, stream>>>(bufF, sumpool, sarr, smax);
  k_attd   <<<128, 256, 0, stream>>>(sarr, smax, ssum);
  k_attp   <<<256, 256, 0, stream>>>(bufF, sarr, smax, ssum, attpool);
  k_mlp    <<<1, 256, 0, stream>>>(sumpool, maxkey, attpool,
                                   Wm1, bm1, Wm2, bm2, Wm3, bm3, out);
}

// Round 3
// 585.048 us; speedup vs baseline: 1.4876x; 1.2981x over previous
//
#include <hip/hip_runtime.h>
#include <hip/hip_fp16.h>
#include <type_traits>

static const long long N_ = 50000;
static const long long E_ = 800000;

typedef __attribute__((ext_vector_type(8))) short bf16x8;
typedef __attribute__((ext_vector_type(4))) float f32x4;

__device__ __forceinline__ float lrelu(float x){ return x >= 0.f ? x : 0.2f*x; }
__device__ __forceinline__ unsigned fkey(float x){
  unsigned u = __float_as_uint(x);
  return (u & 0x80000000u) ? ~u : (u | 0x80000000u);
}
__device__ __forceinline__ float unfkey(unsigned k){
  return __uint_as_float((k & 0x80000000u) ? (k & 0x7fffffffu) : ~k);
}

// ---- column sums of edge_attr [E,4] -> sum_ea[4] ----
__global__ void k_sumea(const float* __restrict__ ea, float* __restrict__ sum_ea){
  __shared__ float lds[256];
  int t = threadIdx.x;
  long long total = E_*4;
  float s = 0.f;
  for (long long i = (long long)blockIdx.x*256 + t; i < total; i += (long long)gridDim.x*256)
    s += ea[i];
  lds[t] = s; __syncthreads();
  for (int st=128; st>=4; st>>=1){ if (t<st) lds[t] += lds[t+st]; __syncthreads(); }
  if (t<4) atomicAdd(&sum_ea[t], lds[t]);
}

// ---- in-degree histogram over dst ----
__global__ void k_deg(const int* __restrict__ ei, int* __restrict__ deg){
  long long e = (long long)blockIdx.x*256 + threadIdx.x;
  if (e < E_) atomicAdd(&deg[ei[E_ + e]], 1);
}

// ---- parallel scan, phase 1: per-block sums of deg (256/block) ----
__global__ void k_scan1(const int* __restrict__ deg, int* __restrict__ bsum){
  __shared__ int lds[256];
  int t = threadIdx.x;
  long long idx = (long long)blockIdx.x*256 + t;
  lds[t] = (idx < N_) ? deg[idx] : 0;
  __syncthreads();
  for (int st=128; st>=1; st>>=1){ if (t<st) lds[t] += lds[t+st]; __syncthreads(); }
  if (t==0) bsum[blockIdx.x] = lds[0];
}

// ---- phase 2: scan block sums (nb <= 256) ----
__global__ void k_scan2(const int* __restrict__ bsum, int* __restrict__ bpre, int nb,
                        int* __restrict__ rowptr){
  __shared__ int lds[256];
  int t = threadIdx.x;
  int v = (t < nb) ? bsum[t] : 0;
  lds[t] = v; __syncthreads();
  for (int off=1; off<256; off<<=1){
    int add = (t>=off) ? lds[t-off] : 0;
    __syncthreads();
    lds[t] += add;
    __syncthreads();
  }
  if (t < nb) bpre[t] = lds[t] - v;     // exclusive
  if (t == 0) rowptr[N_] = (int)E_;
}

// ---- phase 3: local scan + block offset -> rowptr/cursor ----
__global__ void k_scan3(const int* __restrict__ deg, const int* __restrict__ bpre,
                        int* __restrict__ rowptr, int* __restrict__ cursor){
  __shared__ int lds[256];
  int t = threadIdx.x;
  long long idx = (long long)blockIdx.x*256 + t;
  int v = (idx < N_) ? deg[idx] : 0;
  lds[t] = v; __syncthreads();
  for (int off=1; off<256; off<<=1){
    int add = (t>=off) ? lds[t-off] : 0;
    __syncthreads();
    lds[t] += add;
    __syncthreads();
  }
  if (idx < N_){
    int rp = bpre[blockIdx.x] + lds[t] - v;
    rowptr[idx] = rp; cursor[idx] = rp;
  }
}

// ---- tiny: Ae_l[f][h]; loop_ale_l[h] ----
// small layout: [0..15]=Ae0, [16..31]=Ae1, [32..35]=loop0, [36..39]=loop1
__global__ void k_small(const float* __restrict__ We0, const float* __restrict__ ae0,
                        const float* __restrict__ We1, const float* __restrict__ ae1,
                        const float* __restrict__ sum_ea, float* __restrict__ small){
  int t = threadIdx.x; // 64
  if (t < 32){
    int l = t>>4, f = (t>>2)&3, h = t&3;
    const float* We = l ? We1 : We0;
    const float* ae = l ? ae1 : ae0;
    float s = 0.f;
    for (int cc=0; cc<64; cc++) s += We[f*256 + h*64 + cc]*ae[h*64+cc];
    small[l*16 + f*4 + h] = s;
  }
  __syncthreads();
  if (t < 8){
    int l = t>>2, h = t&3;
    const float* Ae = small + l*16;
    const float invE = 1.f/(float)E_;
    float s = 0.f;
    for (int f=0; f<4; f++) s += sum_ea[f]*invE*Ae[f*4+h];
    small[32 + l*4 + h] = s;
  }
}

// ---- scatter edges into CSR slots; al_e for both layers in one 32B record ----
__global__ void k_scatter(const int* __restrict__ ei, const float* __restrict__ ea,
                          int* __restrict__ cursor, int* __restrict__ csr_src,
                          float* __restrict__ ale, const float* __restrict__ small){
  long long e = (long long)blockIdx.x*256 + threadIdx.x;
  if (e >= E_) return;
  int s = ei[e], d = ei[E_+e];
  int pos = atomicAdd(&cursor[d], 1);
  csr_src[pos] = s;
  float4 v = *(const float4*)(ea + e*4);
  float o0[4], o1[4];
  #pragma unroll
  for (int h=0; h<4; h++){
    o0[h] = v.x*small[0+h]  + v.y*small[4+h]  + v.z*small[8+h]  + v.w*small[12+h];
    o1[h] = v.x*small[16+h] + v.y*small[20+h] + v.z*small[24+h] + v.w*small[28+h];
  }
  float* p = ale + (long long)pos*8;
  *(float4*)(p)   = make_float4(o0[0],o0[1],o0[2],o0[3]);
  *(float4*)(p+4) = make_float4(o1[0],o1[1],o1[2],o1[3]);
}

// ---- h0 = x @ W0 (K=5), stored fp16; als0/ald0 from fp32 pre-round values ----
__global__ void k_h0(const float* __restrict__ x, const float* __restrict__ W0,
                     const float* __restrict__ as0, const float* __restrict__ ad0,
                     __half* __restrict__ h0, float* __restrict__ als, float* __restrict__ ald){
  long long wid = ((long long)blockIdx.x*blockDim.x + threadIdx.x) >> 6;
  int lane = threadIdx.x & 63;
  if (wid >= N_) return;
  const float* xr = x + wid*5;
  float xv[5];
  #pragma unroll
  for (int f=0; f<5; f++) xv[f] = xr[f];
  int c = lane*4;
  float a0=0,a1=0,a2=0,a3=0;
  #pragma unroll
  for (int f=0; f<5; f++){
    const float* wr = W0 + f*256 + c;
    a0 += xv[f]*wr[0]; a1 += xv[f]*wr[1]; a2 += xv[f]*wr[2]; a3 += xv[f]*wr[3];
  }
  __half2 p01 = __floats2half2_rn(a0,a1);
  __half2 p23 = __floats2half2_rn(a2,a3);
  uint2 pk = make_uint2(*(unsigned*)&p01, *(unsigned*)&p23);
  *(uint2*)(h0 + wid*256 + c) = pk;
  const float* asp = as0 + c;
  const float* adp = ad0 + c;
  float ss = a0*asp[0]+a1*asp[1]+a2*asp[2]+a3*asp[3];
  float dd = a0*adp[0]+a1*adp[1]+a2*adp[2]+a3*adp[3];
  int head = lane>>4;
  #pragma unroll
  for (int m=1; m<16; m<<=1){ ss += __shfl_xor(ss, m); dd += __shfl_xor(dd, m); }
  if ((lane&15)==0){ als[wid*4+head]=ss; ald[wid*4+head]=dd; }
}

// ---- GAT aggregation: one wave per dst node; 2-edge unrolled online softmax ----
template<typename OutT, bool RELU>
__global__ void k_agg(const __half* __restrict__ hin, const float* __restrict__ als,
                      const float* __restrict__ ald, const int* __restrict__ rowptr,
                      const int* __restrict__ csr_src, const float* __restrict__ ale,
                      const float* __restrict__ small, int loop_off,
                      const float* __restrict__ bias, OutT* __restrict__ out){
  long long wid = ((long long)blockIdx.x*blockDim.x + threadIdx.x) >> 6;
  int lane = threadIdx.x & 63;
  if (wid >= N_) return;
  int head = lane>>4; int c = lane*4;
  float aldv = ald[wid*4+head];
  float a0 = lrelu(als[wid*4+head] + aldv + small[loop_off+head]);
  float m = a0, d = 1.f;
  uint2 pk0 = *(const uint2*)(hin + wid*256 + c);   // self-loop msg, weight exp(0)=1
  float2 f01 = __half22float2(*(__half2*)&pk0.x);
  float2 f23 = __half22float2(*(__half2*)&pk0.y);
  float accx=f01.x, accy=f01.y, accz=f23.x, accw=f23.y;
  int beg = rowptr[wid], end = rowptr[wid+1];
  int i = beg;
  for (; i+1 < end; i += 2){
    int s0 = csr_src[i], s1 = csr_src[i+1];
    float a1 = lrelu(als[(long long)s0*4+head] + aldv + ale[(long long)i*8+head]);
    float a2 = lrelu(als[(long long)s1*4+head] + aldv + ale[(long long)(i+1)*8+head]);
    uint2 pku = *(const uint2*)(hin + (long long)s0*256 + c);
    uint2 pkv = *(const uint2*)(hin + (long long)s1*256 + c);
    float2 u01=__half22float2(*(__half2*)&pku.x), u23=__half22float2(*(__half2*)&pku.y);
    float2 v01=__half22float2(*(__half2*)&pkv.x), v23=__half22float2(*(__half2*)&pkv.y);
    float nm = fmaxf(m, fmaxf(a1, a2));
    float sc = __expf(m - nm);
    float p1 = __expf(a1 - nm);
    float p2 = __expf(a2 - nm);
    d = d*sc + p1 + p2;
    accx = accx*sc + p1*u01.x + p2*v01.x;
    accy = accy*sc + p1*u01.y + p2*v01.y;
    accz = accz*sc + p1*u23.x + p2*v23.x;
    accw = accw*sc + p1*u23.y + p2*v23.y;
    m = nm;
  }
  if (i < end){
    int s0 = csr_src[i];
    float a = lrelu(als[(long long)s0*4+head] + aldv + ale[(long long)i*8+head]);
    uint2 pk = *(const uint2*)(hin + (long long)s0*256 + c);
    float2 g01=__half22float2(*(__half2*)&pk.x), g23=__half22float2(*(__half2*)&pk.y);
    float nm = fmaxf(m, a);
    float sc = __expf(m - nm);
    float p  = __expf(a - nm);
    d = d*sc + p;
    accx = accx*sc + p*g01.x;
    accy = accy*sc + p*g01.y;
    accz = accz*sc + p*g23.x;
    accw = accw*sc + p*g23.y;
    m = nm;
  }
  float inv = 1.f/(d + 1e-16f);
  const float* bp = bias + c;
  float ox = accx*inv + bp[0], oy = accy*inv + bp[1];
  float oz = accz*inv + bp[2], ow = accw*inv + bp[3];
  if (RELU){ ox=fmaxf(ox,0.f); oy=fmaxf(oy,0.f); oz=fmaxf(oz,0.f); ow=fmaxf(ow,0.f); }
  if constexpr (std::is_same<OutT,__half>::value){
    __half2 q01 = __floats2half2_rn(ox,oy);
    __half2 q23 = __floats2half2_rn(oz,ow);
    uint2 qk = make_uint2(*(unsigned*)&q01, *(unsigned*)&q23);
    *(uint2*)(out + wid*256 + c) = qk;
  } else {
    *(float4*)(out + wid*256 + c) = make_float4(ox,oy,oz,ow);
  }
}

// ---- prep: W1 -> hi/lo bf16 in MFMA B-fragment layout ----
__global__ void k_prepB(const float* __restrict__ W1, ushort* __restrict__ Bhi,
                        ushort* __restrict__ Blo){
  int k = blockIdx.x;     // 256
  int n = threadIdx.x;    // 256
  float v = W1[k*256+n];
  unsigned u = __float_as_uint(v);
  ushort hi = (ushort)(u>>16);
  float rem = v - __uint_as_float(u & 0xffff0000u);
  unsigned ur = __float_as_uint(rem);
  ushort lo = (ushort)((ur + 0x7fff + ((ur>>16)&1)) >> 16);
  int t = n>>4, kb = k>>5, q = (k>>3)&3, j = k&7;
  long long idx = ((((long long)t*8+kb)*64 + q*16 + (n&15))<<3) + j;
  Bhi[idx] = hi; Blo[idx] = lo;
}

// ---- h1 = x1 @ W1 via split-bf16 MFMA (3 products); fp16 out; fused als1/ald1 ----
__global__ __launch_bounds__(256) void k_gemm(const float* __restrict__ A,
    const ushort* __restrict__ Bhi, const ushort* __restrict__ Blo,
    __half* __restrict__ Ch, const float* __restrict__ as1, const float* __restrict__ ad1,
    float* __restrict__ als, float* __restrict__ ald){
  __shared__ ushort Ah[32*264];
  __shared__ ushort Al[32*264];
  int t = threadIdx.x;
  long long base = (long long)blockIdx.x*32;
  for (int i=t; i<2048; i+=256){
    int r = i>>6, q4 = i&63;
    float4 v = make_float4(0.f,0.f,0.f,0.f);
    if (base + r < N_) v = *(const float4*)(A + (base+r)*256 + q4*4);
    float vv[4] = {v.x,v.y,v.z,v.w};
    ushort hh[4], ll[4];
    #pragma unroll
    for (int e=0;e<4;e++){
      unsigned u = __float_as_uint(vv[e]);
      hh[e] = (ushort)(u>>16);
      float rem = vv[e] - __uint_as_float(u & 0xffff0000u);
      unsigned ur = __float_as_uint(rem);
      ll[e] = (ushort)((ur + 0x7fff + ((ur>>16)&1)) >> 16);
    }
    int off = r*264 + q4*4;
    *(ushort4*)(Ah+off) = make_ushort4(hh[0],hh[1],hh[2],hh[3]);
    *(ushort4*)(Al+off) = make_ushort4(ll[0],ll[1],ll[2],ll[3]);
  }
  __syncthreads();
  int w = t>>6, lane = t&63, m = lane&15, q = lane>>4;
  int rbase = (w>>1)*16;
  int nhalf = (w&1)*8;
  f32x4 acc[8];
  #pragma unroll
  for (int i=0;i<8;i++) acc[i] = (f32x4){0.f,0.f,0.f,0.f};
  for (int kb=0; kb<8; kb++){
    int aoff = (rbase+m)*264 + kb*32 + q*8;
    bf16x8 ah = *(const bf16x8*)(Ah + aoff);
    bf16x8 al = *(const bf16x8*)(Al + aoff);
    #pragma unroll
    for (int tt=0; tt<8; tt++){
      long long bidx = ((((long long)(nhalf+tt)*8+kb)*64 + lane)<<3);
      bf16x8 bh = *(const bf16x8*)(Bhi + bidx);
      bf16x8 bl = *(const bf16x8*)(Blo + bidx);
      acc[tt] = __builtin_amdgcn_mfma_f32_16x16x32_bf16(ah, bh, acc[tt], 0,0,0);
      acc[tt] = __builtin_amdgcn_mfma_f32_16x16x32_bf16(al, bh, acc[tt], 0,0,0);
      acc[tt] = __builtin_amdgcn_mfma_f32_16x16x32_bf16(ah, bl, acc[tt], 0,0,0);
    }
  }
  float ssv[4][2], ddv[4][2];
  #pragma unroll
  for (int r=0;r<4;r++){ ssv[r][0]=0.f; ssv[r][1]=0.f; ddv[r][0]=0.f; ddv[r][1]=0.f; }
  #pragma unroll
  for (int tt=0; tt<8; tt++){
    int col = (nhalf+tt)*16 + m;
    float as_ = as1[col], ad_ = ad1[col];
    int hh = tt>>2;
    #pragma unroll
    for (int r=0;r<4;r++){
      ssv[r][hh] += acc[tt][r]*as_;
      ddv[r][hh] += acc[tt][r]*ad_;
    }
  }
  #pragma unroll
  for (int r=0;r<4;r++){
    #pragma unroll
    for (int hh=0; hh<2; hh++){
      #pragma unroll
      for (int mm=1; mm<16; mm<<=1){
        ssv[r][hh] += __shfl_xor(ssv[r][hh], mm);
        ddv[r][hh] += __shfl_xor(ddv[r][hh], mm);
      }
    }
  }
  #pragma unroll
  for (int r=0;r<4;r++){
    long long grow = base + rbase + q*4 + r;
    if (grow < N_){
      #pragma unroll
      for (int tt=0; tt<8; tt++)
        Ch[grow*256 + (nhalf+tt)*16 + m] = __float2half(acc[tt][r]);
      if (m==0){
        int hb = (w&1)*2;
        als[grow*4 + hb+0] = ssv[r][0];
        ald[grow*4 + hb+0] = ddv[r][0];
        als[grow*4 + hb+1] = ssv[r][1];
        ald[grow*4 + hb+1] = ddv[r][1];
      }
    }
  }
}

// ---- column-wise sum & max over nodes (fp16 h2) ----
__global__ void k_pool1(const __half* __restrict__ h2, float* __restrict__ sum_pool,
                        unsigned* __restrict__ maxkey){
  int c = threadIdx.x; // 256
  float s = 0.f; float m = -3.4e38f;
  for (long long n = blockIdx.x; n < N_; n += gridDim.x){
    float v = __half2float(h2[n*256+c]); s += v; m = fmaxf(m, v);
  }
  atomicAdd(&sum_pool[c], s);
  atomicMax(&maxkey[c], fkey(m));
}

// ---- s[n] = dot(h2[n], mean_pool); track global max ----
__global__ void k_atts(const __half* __restrict__ h2, const float* __restrict__ sum_pool,
                       float* __restrict__ sarr, unsigned* __restrict__ smax){
  __shared__ float lmax[4];
  int t = threadIdx.x; int lane = t&63; int w = t>>6;
  const float invN = 1.f/(float)N_;
  int c = lane*4;
  float4 mp = *(const float4*)(sum_pool + c);
  float mymax = -3.4e38f;
  for (long long wid = (long long)blockIdx.x*4 + w; wid < N_; wid += (long long)gridDim.x*4){
    uint2 pk = *(const uint2*)(h2 + wid*256 + c);
    float2 a01 = __half22float2(*(__half2*)&pk.x);
    float2 a23 = __half22float2(*(__half2*)&pk.y);
    float s = (a01.x*mp.x + a01.y*mp.y + a23.x*mp.z + a23.y*mp.w)*invN;
    #pragma unroll
    for (int m=1; m<64; m<<=1) s += __shfl_xor(s, m);
    if (lane==0) sarr[wid] = s;
    mymax = fmaxf(mymax, s);
  }
  if (lane==0) lmax[w] = mymax;
  __syncthreads();
  if (t==0){
    float mm = fmaxf(fmaxf(lmax[0],lmax[1]), fmaxf(lmax[2],lmax[3]));
    atomicMax(smax, fkey(mm));
  }
}

// ---- sum of exp(s - smax) ----
__global__ void k_attd(const float* __restrict__ sarr, const unsigned* __restrict__ smax,
                       float* __restrict__ ssum){
  __shared__ float lds[256];
  int t = threadIdx.x;
  float mx = unfkey(*smax);
  float s = 0.f;
  for (long long i = (long long)blockIdx.x*256 + t; i < N_; i += (long long)gridDim.x*256)
    s += __expf(sarr[i] - mx);
  lds[t] = s; __syncthreads();
  for (int st=128; st>=1; st>>=1){ if (t<st) lds[t]+=lds[t+st]; __syncthreads(); }
  if (t==0) atomicAdd(ssum, lds[0]);
}

// ---- att_pool[c] = sum_n h2[n][c]*softmax(s)[n] ----
__global__ void k_attp(const __half* __restrict__ h2, const float* __restrict__ sarr,
                       const unsigned* __restrict__ smax, const float* __restrict__ ssum,
                       float* __restrict__ att_pool){
  int c = threadIdx.x; // 256
  float mx = unfkey(*smax);
  float inv = 1.f/(*ssum);
  float acc = 0.f;
  for (long long n = blockIdx.x; n < N_; n += gridDim.x){
    float w = __expf(sarr[n]-mx)*inv;
    acc += __half2float(h2[n*256+c])*w;
  }
  atomicAdd(&att_pool[c], acc);
}

// ---- final MLP: [768] -> 128 -> 64 -> 128, split-K across 512 threads ----
__global__ void k_mlp(const float* __restrict__ sum_pool, const unsigned* __restrict__ maxkey,
                      const float* __restrict__ att_pool,
                      const float* __restrict__ Wm1, const float* __restrict__ bm1,
                      const float* __restrict__ Wm2, const float* __restrict__ bm2,
                      const float* __restrict__ Wm3, const float* __restrict__ bm3,
                      float* __restrict__ out){
  __shared__ float comb[768];
  __shared__ float z1p[4][128]; __shared__ float z1[128];
  __shared__ float z2p[8][64];  __shared__ float z2[64];
  __shared__ float z3p[4][128];
  int t = threadIdx.x; // 512
  const float invN = 1.f/(float)N_;
  for (int i=t; i<768; i+=512){
    float v;
    if (i < 256)      v = sum_pool[i]*invN;
    else if (i < 512) v = unfkey(maxkey[i-256]);
    else              v = att_pool[i-512];
    comb[i] = v;
  }
  __syncthreads();
  { int n = t&127, part = t>>7;     // 4 parts x 192
    float a = 0.f;
    for (int f=part*192; f<part*192+192; f++) a += comb[f]*Wm1[f*128+n];
    z1p[part][n] = a;
  }
  __syncthreads();
  if (t < 128)
    z1[t] = fmaxf(bm1[t] + z1p[0][t]+z1p[1][t]+z1p[2][t]+z1p[3][t], 0.f);
  __syncthreads();
  { int n = t&63, part = t>>6;      // 8 parts x 16
    float a = 0.f;
    for (int f=part*16; f<part*16+16; f++) a += z1[f]*Wm2[f*64+n];
    z2p[part][n] = a;
  }
  __syncthreads();
  if (t < 64){
    float a = bm2[t];
    #pragma unroll
    for (int p=0;p<8;p++) a += z2p[p][t];
    z2[t] = fmaxf(a, 0.f);
  }
  __syncthreads();
  { int n = t&127, part = t>>7;     // 4 parts x 16
    float a = 0.f;
    for (int f=part*16; f<part*16+16; f++) a += z2[f]*Wm3[f*128+n];
    z3p[part][n] = a;
  }
  __syncthreads();
  if (t < 128)
    out[t] = bm3[t] + z3p[0][t]+z3p[1][t]+z3p[2][t]+z3p[3][t];
}

extern "C" void kernel_launch(void* const* d_in, const int* in_sizes, int n_in,
                              void* d_out, int out_size, void* d_ws, size_t ws_size,
                              hipStream_t stream){
  (void)in_sizes; (void)n_in; (void)out_size; (void)ws_size;
  const float* x   = (const float*)d_in[0];
  const int*   ei  = (const int*)d_in[1];
  const float* ea  = (const float*)d_in[2];
  const float* W0  = (const float*)d_in[3];
  const float* as0 = (const float*)d_in[4];
  const float* ad0 = (const float*)d_in[5];
  const float* We0 = (const float*)d_in[6];
  const float* ae0 = (const float*)d_in[7];
  const float* b0  = (const float*)d_in[8];
  const float* W1  = (const float*)d_in[9];
  const float* as1 = (const float*)d_in[10];
  const float* ad1 = (const float*)d_in[11];
  const float* We1 = (const float*)d_in[12];
  const float* ae1 = (const float*)d_in[13];
  const float* b1  = (const float*)d_in[14];
  const float* Wm1 = (const float*)d_in[15];
  const float* bm1 = (const float*)d_in[16];
  const float* Wm2 = (const float*)d_in[17];
  const float* bm2 = (const float*)d_in[18];
  const float* Wm3 = (const float*)d_in[19];
  const float* bm3 = (const float*)d_in[20];
  float* out = (float*)d_out;

  char* ws = (char*)d_ws;
  size_t o = 0;
  auto alloc = [&](size_t bytes)->size_t{
    size_t r = o; o = (o + bytes + 255) & ~(size_t)255; return r;
  };
  size_t o_bufF   = alloc((size_t)N_*256*4);   // x1 (fp32), then h2 (fp16)
  size_t o_bufH   = alloc((size_t)N_*256*2);   // h0, then h1 (fp16)
  size_t o_als0   = alloc((size_t)N_*4*4);
  size_t o_ald0   = alloc((size_t)N_*4*4);
  size_t o_als1   = alloc((size_t)N_*4*4);
  size_t o_ald1   = alloc((size_t)N_*4*4);
  size_t o_rowptr = alloc((size_t)(N_+1)*4);
  size_t o_cursor = alloc((size_t)N_*4);
  size_t o_csrsrc = alloc((size_t)E_*4);
  size_t o_ale    = alloc((size_t)E_*8*4);     // 32B/edge: [ale0 x4 | ale1 x4]
  size_t o_sarr   = alloc((size_t)N_*4);
  size_t o_Bhi    = alloc((size_t)256*256*2);
  size_t o_Blo    = alloc((size_t)256*256*2);
  size_t o_bsum   = alloc(256*4);
  size_t o_bpre   = alloc(256*4);
  // --- zero block ---
  size_t zstart   = o;
  size_t o_deg    = alloc((size_t)N_*4);
  size_t o_sumea  = alloc(16);
  size_t o_sumpool= alloc(256*4);
  size_t o_maxkey = alloc(256*4);
  size_t o_attpool= alloc(256*4);
  size_t o_smax   = alloc(4);
  size_t o_ssum   = alloc(4);
  size_t zend     = o;
  size_t o_small  = alloc(40*4);

  float*  bufF   = (float*)(ws + o_bufF);
  __half* bufH   = (__half*)(ws + o_bufH);
  __half* h2h    = (__half*)(ws + o_bufF);     // reuse bufF region for fp16 h2
  float* pals0  = (float*)(ws + o_als0);
  float* pald0  = (float*)(ws + o_ald0);
  float* pals1  = (float*)(ws + o_als1);
  float* pald1  = (float*)(ws + o_ald1);
  int*   rowptr = (int*)(ws + o_rowptr);
  int*   cursor = (int*)(ws + o_cursor);
  int*   csrsrc = (int*)(ws + o_csrsrc);
  float* ale    = (float*)(ws + o_ale);
  float* sarr   = (float*)(ws + o_sarr);
  ushort* Bhi   = (ushort*)(ws + o_Bhi);
  ushort* Blo   = (ushort*)(ws + o_Blo);
  int*   bsum   = (int*)(ws + o_bsum);
  int*   bpre   = (int*)(ws + o_bpre);
  int*   deg    = (int*)(ws + o_deg);
  float* sumea  = (float*)(ws + o_sumea);
  float* sumpool= (float*)(ws + o_sumpool);
  unsigned* maxkey = (unsigned*)(ws + o_maxkey);
  float* attpool= (float*)(ws + o_attpool);
  unsigned* smax= (unsigned*)(ws + o_smax);
  float* ssum   = (float*)(ws + o_ssum);
  float* small  = (float*)(ws + o_small);

  hipMemsetAsync(ws + zstart, 0, zend - zstart, stream);

  int eb = (int)((E_ + 255)/256);          // 3125
  int nb_wave = (int)((N_*64 + 255)/256);  // 12500 (one wave per node)
  int gb = (int)((N_ + 31)/32);            // 1563 gemm blocks
  int sb = (int)((N_ + 255)/256);          // 196 scan blocks

  k_sumea  <<<1024, 256, 0, stream>>>(ea, sumea);
  k_deg    <<<eb, 256, 0, stream>>>(ei, deg);
  k_prepB  <<<256, 256, 0, stream>>>(W1, Bhi, Blo);
  k_scan1  <<<sb, 256, 0, stream>>>(deg, bsum);
  k_scan2  <<<1, 256, 0, stream>>>(bsum, bpre, sb, rowptr);
  k_scan3  <<<sb, 256, 0, stream>>>(deg, bpre, rowptr, cursor);
  k_small  <<<1, 64, 0, stream>>>(We0, ae0, We1, ae1, sumea, small);
  k_scatter<<<eb, 256, 0, stream>>>(ei, ea, cursor, csrsrc, ale, small);
  k_h0     <<<nb_wave, 256, 0, stream>>>(x, W0, as0, ad0, bufH, pals0, pald0);
  k_agg<float,true>  <<<nb_wave, 256, 0, stream>>>(bufH, pals0, pald0, rowptr, csrsrc,
                                         ale + 0, small, 32, b0, bufF);    // x1 fp32
  k_gemm   <<<gb, 256, 0, stream>>>(bufF, Bhi, Blo, bufH, as1, ad1, pals1, pald1); // h1 fp16
  k_agg<__half,false><<<nb_wave, 256, 0, stream>>>(bufH, pals1, pald1, rowptr, csrsrc,
                                         ale + 4, small, 36, b1, h2h);     // h2 fp16
  k_pool1  <<<256, 256, 0, stream>>>(h2h, sumpool, maxkey);
  k_atts   <<<1024, 256, 0, stream>>>(h2h, sumpool, sarr, smax);
  k_attd   <<<128, 256, 0, stream>>>(sarr, smax, ssum);
  k_attp   <<<256, 256, 0, stream>>>(h2h, sarr, smax, ssum, attpool);
  k_mlp    <<<1, 512, 0, stream>>>(sumpool, maxkey, attpool,
                                   Wm1, bm1, Wm2, bm2, Wm3, bm3, out);
}

// Round 4
// 562.893 us; speedup vs baseline: 1.5461x; 1.0394x over previous
//
#include <hip/hip_runtime.h>
#include <hip/hip_fp16.h>
#include <type_traits>

static const long long N_ = 50000;
static const long long E_ = 800000;
#define LOG2E 1.44269504088896f

typedef __attribute__((ext_vector_type(8))) short bf16x8;
typedef __attribute__((ext_vector_type(4))) float f32x4;

__device__ __forceinline__ float lrelu(float x){ return x >= 0.f ? x : 0.2f*x; }
__device__ __forceinline__ unsigned fkey(float x){
  unsigned u = __float_as_uint(x);
  return (u & 0x80000000u) ? ~u : (u | 0x80000000u);
}
__device__ __forceinline__ float unfkey(unsigned k){
  return __uint_as_float((k & 0x80000000u) ? (k & 0x7fffffffu) : ~k);
}
__device__ __forceinline__ unsigned h2u(__half2 h){ return *(unsigned*)&h; }

// ---- fused prologue: deg histogram + ea column sums + W1 bf16-split prep ----
__global__ void k_pre(const int* __restrict__ ei, int* __restrict__ deg,
                      const float* __restrict__ ea, float* __restrict__ sum_ea,
                      const float* __restrict__ W1, ushort* __restrict__ Bhi,
                      ushort* __restrict__ Blo){
  int t = threadIdx.x;
  long long e = (long long)blockIdx.x*256 + t;
  if (e < E_) atomicAdd(&deg[ei[E_ + e]], 1);
  if (blockIdx.x < 256){
    int k = blockIdx.x, n = t;
    float v = W1[k*256+n];
    unsigned u = __float_as_uint(v);
    ushort hi = (ushort)(u>>16);
    float rem = v - __uint_as_float(u & 0xffff0000u);
    unsigned ur = __float_as_uint(rem);
    ushort lo = (ushort)((ur + 0x7fff + ((ur>>16)&1)) >> 16);
    int tl = n>>4, kb = k>>5, q = (k>>3)&3, j = k&7;
    long long idx = ((((long long)tl*8+kb)*64 + q*16 + (n&15))<<3) + j;
    Bhi[idx] = hi; Blo[idx] = lo;
  }
  __shared__ float lds[256];
  float s = 0.f;
  for (long long i = (long long)blockIdx.x*256 + t; i < E_*4; i += (long long)gridDim.x*256)
    s += ea[i];
  lds[t] = s; __syncthreads();
  for (int st=128; st>=4; st>>=1){ if (t<st) lds[t] += lds[t+st]; __syncthreads(); }
  if (t<4) atomicAdd(&sum_ea[t], lds[t]);
}

// ---- parallel scan, phase 1: per-block sums of deg ----
__global__ void k_scan1(const int* __restrict__ deg, int* __restrict__ bsum){
  __shared__ int lds[256];
  int t = threadIdx.x;
  long long idx = (long long)blockIdx.x*256 + t;
  lds[t] = (idx < N_) ? deg[idx] : 0;
  __syncthreads();
  for (int st=128; st>=1; st>>=1){ if (t<st) lds[t] += lds[t+st]; __syncthreads(); }
  if (t==0) bsum[blockIdx.x] = lds[0];
}

// ---- phase 2: scan block sums (nb <= 256) + fused "small" precompute ----
// small layout: [0..15]=Ae0*log2e, [16..31]=Ae1*log2e, [32..35]=loop0, [36..39]=loop1
__global__ void k_scan2(const int* __restrict__ bsum, int* __restrict__ bpre, int nb,
                        int* __restrict__ rowptr,
                        const float* __restrict__ We0, const float* __restrict__ ae0,
                        const float* __restrict__ We1, const float* __restrict__ ae1,
                        const float* __restrict__ sum_ea, float* __restrict__ small){
  __shared__ int lds[256];
  int t = threadIdx.x;
  int v = (t < nb) ? bsum[t] : 0;
  lds[t] = v; __syncthreads();
  for (int off=1; off<256; off<<=1){
    int add = (t>=off) ? lds[t-off] : 0;
    __syncthreads();
    lds[t] += add;
    __syncthreads();
  }
  if (t < nb) bpre[t] = lds[t] - v;     // exclusive
  if (t == 0) rowptr[N_] = (int)E_;
  // --- small (scaled by log2e) ---
  if (t < 32){
    int l = t>>4, f = (t>>2)&3, h = t&3;
    const float* We = l ? We1 : We0;
    const float* ae = l ? ae1 : ae0;
    float s = 0.f;
    for (int cc=0; cc<64; cc++) s += We[f*256 + h*64 + cc]*ae[h*64+cc];
    small[l*16 + f*4 + h] = s * LOG2E;
  }
  __syncthreads();
  if (t < 8){
    int l = t>>2, h = t&3;
    const float* Ae = small + l*16;       // already scaled
    const float invE = 1.f/(float)E_;
    float s = 0.f;
    for (int f=0; f<4; f++) s += sum_ea[f]*invE*Ae[f*4+h];
    small[32 + l*4 + h] = s;
  }
}

// ---- phase 3: local scan + block offset -> rowptr/cursor ----
__global__ void k_scan3(const int* __restrict__ deg, const int* __restrict__ bpre,
                        int* __restrict__ rowptr, int* __restrict__ cursor){
  __shared__ int lds[256];
  int t = threadIdx.x;
  long long idx = (long long)blockIdx.x*256 + t;
  int v = (idx < N_) ? deg[idx] : 0;
  lds[t] = v; __syncthreads();
  for (int off=1; off<256; off<<=1){
    int add = (t>=off) ? lds[t-off] : 0;
    __syncthreads();
    lds[t] += add;
    __syncthreads();
  }
  if (idx < N_){
    int rp = bpre[blockIdx.x] + lds[t] - v;
    rowptr[idx] = rp; cursor[idx] = rp;
  }
}

// ---- scatter edges into CSR slots; log2-scaled al_e (both layers) as fp16 x8 ----
__global__ void k_scatter(const int* __restrict__ ei, const float* __restrict__ ea,
                          int* __restrict__ cursor, int* __restrict__ csr_src,
                          __half* __restrict__ aleh, const float* __restrict__ small){
  long long e = (long long)blockIdx.x*256 + threadIdx.x;
  if (e >= E_) return;
  int s = ei[e], d = ei[E_+e];
  int pos = atomicAdd(&cursor[d], 1);
  csr_src[pos] = s;
  float4 v = *(const float4*)(ea + e*4);
  float o0[4], o1[4];
  #pragma unroll
  for (int h=0; h<4; h++){
    o0[h] = v.x*small[0+h]  + v.y*small[4+h]  + v.z*small[8+h]  + v.w*small[12+h];
    o1[h] = v.x*small[16+h] + v.y*small[20+h] + v.z*small[24+h] + v.w*small[28+h];
  }
  uint4 pk = make_uint4(h2u(__floats2half2_rn(o0[0],o0[1])),
                        h2u(__floats2half2_rn(o0[2],o0[3])),
                        h2u(__floats2half2_rn(o1[0],o1[1])),
                        h2u(__floats2half2_rn(o1[2],o1[3])));
  *(uint4*)(aleh + (long long)pos*8) = pk;
}

// ---- h0 = x @ W0 (K=5), stored fp16; als0/ald0 (log2-scaled) ----
__global__ void k_h0(const float* __restrict__ x, const float* __restrict__ W0,
                     const float* __restrict__ as0, const float* __restrict__ ad0,
                     __half* __restrict__ h0, float* __restrict__ als, float* __restrict__ ald){
  int wid = (int)(((long long)blockIdx.x*blockDim.x + threadIdx.x) >> 6);
  int lane = threadIdx.x & 63;
  if (wid >= (int)N_) return;
  const float* xr = x + wid*5;
  float xv[5];
  #pragma unroll
  for (int f=0; f<5; f++) xv[f] = xr[f];
  int c = lane*4;
  float a0=0,a1=0,a2=0,a3=0;
  #pragma unroll
  for (int f=0; f<5; f++){
    const float* wr = W0 + f*256 + c;
    a0 += xv[f]*wr[0]; a1 += xv[f]*wr[1]; a2 += xv[f]*wr[2]; a3 += xv[f]*wr[3];
  }
  __half2 p01 = __floats2half2_rn(a0,a1);
  __half2 p23 = __floats2half2_rn(a2,a3);
  uint2 pk = make_uint2(h2u(p01), h2u(p23));
  *(uint2*)(h0 + wid*256 + c) = pk;
  const float* asp = as0 + c;
  const float* adp = ad0 + c;
  float ss = a0*asp[0]+a1*asp[1]+a2*asp[2]+a3*asp[3];
  float dd = a0*adp[0]+a1*adp[1]+a2*adp[2]+a3*adp[3];
  int head = lane>>4;
  #pragma unroll
  for (int m=1; m<16; m<<=1){ ss += __shfl_xor(ss, m); dd += __shfl_xor(dd, m); }
  if ((lane&15)==0){ als[wid*4+head]=ss*LOG2E; ald[wid*4+head]=dd*LOG2E; }
}

// ---- GAT aggregation: one wave/node; 4-edge unroll, dual online-softmax states ----
template<typename OutT, bool RELU>
__global__ __launch_bounds__(256) void k_agg(const __half* __restrict__ hin,
    const float* __restrict__ als, const float* __restrict__ ald,
    const int* __restrict__ rowptr, const int* __restrict__ csr_src,
    const __half* __restrict__ aleh,   // already offset by layer (0 or 4)
    const float* __restrict__ small, int loop_off,
    const float* __restrict__ bias, OutT* __restrict__ out){
  int wid = (int)(((long long)blockIdx.x*256 + threadIdx.x) >> 6);
  int lane = threadIdx.x & 63;
  if (wid >= (int)N_) return;
  int head = lane>>4, c = lane*4;
  const uint2* hp = (const uint2*)hin;
  float aldv = ald[wid*4+head];
  float aS = lrelu(als[wid*4+head] + aldv + small[loop_off+head]);
  float mA = aS, dA = 1.f;
  uint2 pk0 = hp[wid*64 + lane];
  float2 f01 = __half22float2(*(__half2*)&pk0.x);
  float2 f23 = __half22float2(*(__half2*)&pk0.y);
  float aAx=f01.x, aAy=f01.y, aAz=f23.x, aAw=f23.y;
  float mB=-1e30f, dB=0.f, aBx=0.f, aBy=0.f, aBz=0.f, aBw=0.f;
  int beg = rowptr[wid], end = rowptr[wid+1];
  int i = beg;
  for (; i+3 < end; i+=4){
    int s0=csr_src[i], s1=csr_src[i+1], s2=csr_src[i+2], s3=csr_src[i+3];
    float t0=als[s0*4+head], t1=als[s1*4+head];
    float t2=als[s2*4+head], t3=als[s3*4+head];
    float e0=__half2float(aleh[i*8+head]);
    float e1=__half2float(aleh[(i+1)*8+head]);
    float e2=__half2float(aleh[(i+2)*8+head]);
    float e3=__half2float(aleh[(i+3)*8+head]);
    uint2 r0=hp[s0*64+lane], r1=hp[s1*64+lane];
    uint2 r2=hp[s2*64+lane], r3=hp[s3*64+lane];
    float a0=lrelu(t0+aldv+e0), a1=lrelu(t1+aldv+e1);
    float a2=lrelu(t2+aldv+e2), a3=lrelu(t3+aldv+e3);
    {
      float nm = fmaxf(mA, fmaxf(a0,a1));
      float sc = exp2f(mA-nm), p0 = exp2f(a0-nm), p1 = exp2f(a1-nm);
      float2 u01=__half22float2(*(__half2*)&r0.x), u23=__half22float2(*(__half2*)&r0.y);
      float2 v01=__half22float2(*(__half2*)&r1.x), v23=__half22float2(*(__half2*)&r1.y);
      dA  = dA*sc + p0 + p1;
      aAx = aAx*sc + p0*u01.x + p1*v01.x;
      aAy = aAy*sc + p0*u01.y + p1*v01.y;
      aAz = aAz*sc + p0*u23.x + p1*v23.x;
      aAw = aAw*sc + p0*u23.y + p1*v23.y;
      mA = nm;
    }
    {
      float nm = fmaxf(mB, fmaxf(a2,a3));
      float sc = exp2f(mB-nm), p2 = exp2f(a2-nm), p3 = exp2f(a3-nm);
      float2 u01=__half22float2(*(__half2*)&r2.x), u23=__half22float2(*(__half2*)&r2.y);
      float2 v01=__half22float2(*(__half2*)&r3.x), v23=__half22float2(*(__half2*)&r3.y);
      dB  = dB*sc + p2 + p3;
      aBx = aBx*sc + p2*u01.x + p3*v01.x;
      aBy = aBy*sc + p2*u01.y + p3*v01.y;
      aBz = aBz*sc + p2*u23.x + p3*v23.x;
      aBw = aBw*sc + p2*u23.y + p3*v23.y;
      mB = nm;
    }
  }
  for (; i < end; i++){
    int s0 = csr_src[i];
    float e0 = __half2float(aleh[i*8+head]);
    float a = lrelu(als[s0*4+head] + aldv + e0);
    uint2 r = hp[s0*64+lane];
    float nm = fmaxf(mA, a);
    float sc = exp2f(mA-nm), p = exp2f(a-nm);
    float2 g01=__half22float2(*(__half2*)&r.x), g23=__half22float2(*(__half2*)&r.y);
    dA  = dA*sc + p;
    aAx = aAx*sc + p*g01.x;
    aAy = aAy*sc + p*g01.y;
    aAz = aAz*sc + p*g23.x;
    aAw = aAw*sc + p*g23.y;
    mA = nm;
  }
  // merge B into A
  float nm = fmaxf(mA, mB);
  float sA = exp2f(mA-nm), sB = exp2f(mB-nm);
  float d  = dA*sA + dB*sB;
  float ax = aAx*sA + aBx*sB, ay = aAy*sA + aBy*sB;
  float az = aAz*sA + aBz*sB, aw = aAw*sA + aBw*sB;
  float inv = 1.f/(d + 1e-16f);
  const float* bp = bias + c;
  float ox = ax*inv + bp[0], oy = ay*inv + bp[1];
  float oz = az*inv + bp[2], ow = aw*inv + bp[3];
  if (RELU){ ox=fmaxf(ox,0.f); oy=fmaxf(oy,0.f); oz=fmaxf(oz,0.f); ow=fmaxf(ow,0.f); }
  if constexpr (std::is_same<OutT,__half>::value){
    uint2 qk = make_uint2(h2u(__floats2half2_rn(ox,oy)), h2u(__floats2half2_rn(oz,ow)));
    *(uint2*)(out + wid*256 + c) = qk;
  } else {
    *(float4*)(out + wid*256 + c) = make_float4(ox,oy,oz,ow);
  }
}

// ---- h1 = x1 @ W1 via split-bf16 MFMA (3 products); fp16 out; fused als1/ald1 ----
__global__ __launch_bounds__(256) void k_gemm(const float* __restrict__ A,
    const ushort* __restrict__ Bhi, const ushort* __restrict__ Blo,
    __half* __restrict__ Ch, const float* __restrict__ as1, const float* __restrict__ ad1,
    float* __restrict__ als, float* __restrict__ ald){
  __shared__ ushort Ah[32*264];
  __shared__ ushort Al[32*264];
  int t = threadIdx.x;
  long long base = (long long)blockIdx.x*32;
  for (int i=t; i<2048; i+=256){
    int r = i>>6, q4 = i&63;
    float4 v = make_float4(0.f,0.f,0.f,0.f);
    if (base + r < N_) v = *(const float4*)(A + (base+r)*256 + q4*4);
    float vv[4] = {v.x,v.y,v.z,v.w};
    ushort hh[4], ll[4];
    #pragma unroll
    for (int e=0;e<4;e++){
      unsigned u = __float_as_uint(vv[e]);
      hh[e] = (ushort)(u>>16);
      float rem = vv[e] - __uint_as_float(u & 0xffff0000u);
      unsigned ur = __float_as_uint(rem);
      ll[e] = (ushort)((ur + 0x7fff + ((ur>>16)&1)) >> 16);
    }
    int off = r*264 + q4*4;
    *(ushort4*)(Ah+off) = make_ushort4(hh[0],hh[1],hh[2],hh[3]);
    *(ushort4*)(Al+off) = make_ushort4(ll[0],ll[1],ll[2],ll[3]);
  }
  __syncthreads();
  int w = t>>6, lane = t&63, m = lane&15, q = lane>>4;
  int rbase = (w>>1)*16;
  int nhalf = (w&1)*8;
  f32x4 acc[8];
  #pragma unroll
  for (int i=0;i<8;i++) acc[i] = (f32x4){0.f,0.f,0.f,0.f};
  for (int kb=0; kb<8; kb++){
    int aoff = (rbase+m)*264 + kb*32 + q*8;
    bf16x8 ah = *(const bf16x8*)(Ah + aoff);
    bf16x8 al = *(const bf16x8*)(Al + aoff);
    #pragma unroll
    for (int tt=0; tt<8; tt++){
      long long bidx = ((((long long)(nhalf+tt)*8+kb)*64 + lane)<<3);
      bf16x8 bh = *(const bf16x8*)(Bhi + bidx);
      bf16x8 bl = *(const bf16x8*)(Blo + bidx);
      acc[tt] = __builtin_amdgcn_mfma_f32_16x16x32_bf16(ah, bh, acc[tt], 0,0,0);
      acc[tt] = __builtin_amdgcn_mfma_f32_16x16x32_bf16(al, bh, acc[tt], 0,0,0);
      acc[tt] = __builtin_amdgcn_mfma_f32_16x16x32_bf16(ah, bl, acc[tt], 0,0,0);
    }
  }
  float ssv[4][2], ddv[4][2];
  #pragma unroll
  for (int r=0;r<4;r++){ ssv[r][0]=0.f; ssv[r][1]=0.f; ddv[r][0]=0.f; ddv[r][1]=0.f; }
  #pragma unroll
  for (int tt=0; tt<8; tt++){
    int col = (nhalf+tt)*16 + m;
    float as_ = as1[col], ad_ = ad1[col];
    int hh = tt>>2;
    #pragma unroll
    for (int r=0;r<4;r++){
      ssv[r][hh] += acc[tt][r]*as_;
      ddv[r][hh] += acc[tt][r]*ad_;
    }
  }
  #pragma unroll
  for (int r=0;r<4;r++){
    #pragma unroll
    for (int hh=0; hh<2; hh++){
      #pragma unroll
      for (int mm=1; mm<16; mm<<=1){
        ssv[r][hh] += __shfl_xor(ssv[r][hh], mm);
        ddv[r][hh] += __shfl_xor(ddv[r][hh], mm);
      }
    }
  }
  #pragma unroll
  for (int r=0;r<4;r++){
    long long grow = base + rbase + q*4 + r;
    if (grow < N_){
      #pragma unroll
      for (int tt=0; tt<8; tt++)
        Ch[grow*256 + (nhalf+tt)*16 + m] = __float2half(acc[tt][r]);
      if (m==0){
        int hb = (w&1)*2;
        als[grow*4 + hb+0] = ssv[r][0]*LOG2E;
        ald[grow*4 + hb+0] = ddv[r][0]*LOG2E;
        als[grow*4 + hb+1] = ssv[r][1]*LOG2E;
        ald[grow*4 + hb+1] = ddv[r][1]*LOG2E;
      }
    }
  }
}

// ---- column-wise sum & max over nodes (fp16 h2) ----
__global__ void k_pool1(const __half* __restrict__ h2, float* __restrict__ sum_pool,
                        unsigned* __restrict__ maxkey){
  int c = threadIdx.x; // 256
  float s = 0.f; float m = -3.4e38f;
  for (long long n = blockIdx.x; n < N_; n += gridDim.x){
    float v = __half2float(h2[n*256+c]); s += v; m = fmaxf(m, v);
  }
  atomicAdd(&sum_pool[c], s);
  atomicMax(&maxkey[c], fkey(m));
}

// ---- s[n] = dot(h2[n], mean_pool); track global max ----
__global__ void k_atts(const __half* __restrict__ h2, const float* __restrict__ sum_pool,
                       float* __restrict__ sarr, unsigned* __restrict__ smax){
  __shared__ float lmax[4];
  int t = threadIdx.x; int lane = t&63; int w = t>>6;
  const float invN = 1.f/(float)N_;
  int c = lane*4;
  float4 mp = *(const float4*)(sum_pool + c);
  float mymax = -3.4e38f;
  for (long long wid = (long long)blockIdx.x*4 + w; wid < N_; wid += (long long)gridDim.x*4){
    uint2 pk = *(const uint2*)(h2 + wid*256 + c);
    float2 a01 = __half22float2(*(__half2*)&pk.x);
    float2 a23 = __half22float2(*(__half2*)&pk.y);
    float s = (a01.x*mp.x + a01.y*mp.y + a23.x*mp.z + a23.y*mp.w)*invN;
    #pragma unroll
    for (int m=1; m<64; m<<=1) s += __shfl_xor(s, m);
    if (lane==0) sarr[wid] = s;
    mymax = fmaxf(mymax, s);
  }
  if (lane==0) lmax[w] = mymax;
  __syncthreads();
  if (t==0){
    float mm = fmaxf(fmaxf(lmax[0],lmax[1]), fmaxf(lmax[2],lmax[3]));
    atomicMax(smax, fkey(mm));
  }
}

// ---- sum of exp(s - smax) ----
__global__ void k_attd(const float* __restrict__ sarr, const unsigned* __restrict__ smax,
                       float* __restrict__ ssum){
  __shared__ float lds[256];
  int t = threadIdx.x;
  float mx = unfkey(*smax);
  float s = 0.f;
  for (long long i = (long long)blockIdx.x*256 + t; i < N_; i += (long long)gridDim.x*256)
    s += __expf(sarr[i] - mx);
  lds[t] = s; __syncthreads();
  for (int st=128; st>=1; st>>=1){ if (t<st) lds[t]+=lds[t+st]; __syncthreads(); }
  if (t==0) atomicAdd(ssum, lds[0]);
}

// ---- att_pool[c] = sum_n h2[n][c]*softmax(s)[n] ----
__global__ void k_attp(const __half* __restrict__ h2, const float* __restrict__ sarr,
                       const unsigned* __restrict__ smax, const float* __restrict__ ssum,
                       float* __restrict__ att_pool){
  int c = threadIdx.x; // 256
  float mx = unfkey(*smax);
  float inv = 1.f/(*ssum);
  float acc = 0.f;
  for (long long n = blockIdx.x; n < N_; n += gridDim.x){
    float w = __expf(sarr[n]-mx)*inv;
    acc += __half2float(h2[n*256+c])*w;
  }
  atomicAdd(&att_pool[c], acc);
}

// ---- final MLP: [768] -> 128 -> 64 -> 128, split-K across 512 threads ----
__global__ void k_mlp(const float* __restrict__ sum_pool, const unsigned* __restrict__ maxkey,
                      const float* __restrict__ att_pool,
                      const float* __restrict__ Wm1, const float* __restrict__ bm1,
                      const float* __restrict__ Wm2, const float* __restrict__ bm2,
                      const float* __restrict__ Wm3, const float* __restrict__ bm3,
                      float* __restrict__ out){
  __shared__ float comb[768];
  __shared__ float z1p[4][128]; __shared__ float z1[128];
  __shared__ float z2p[8][64];  __shared__ float z2[64];
  __shared__ float z3p[4][128];
  int t = threadIdx.x; // 512
  const float invN = 1.f/(float)N_;
  for (int i=t; i<768; i+=512){
    float v;
    if (i < 256)      v = sum_pool[i]*invN;
    else if (i < 512) v = unfkey(maxkey[i-256]);
    else              v = att_pool[i-512];
    comb[i] = v;
  }
  __syncthreads();
  { int n = t&127, part = t>>7;
    float a = 0.f;
    for (int f=part*192; f<part*192+192; f++) a += comb[f]*Wm1[f*128+n];
    z1p[part][n] = a;
  }
  __syncthreads();
  if (t < 128)
    z1[t] = fmaxf(bm1[t] + z1p[0][t]+z1p[1][t]+z1p[2][t]+z1p[3][t], 0.f);
  __syncthreads();
  { int n = t&63, part = t>>6;
    float a = 0.f;
    for (int f=part*16; f<part*16+16; f++) a += z1[f]*Wm2[f*64+n];
    z2p[part][n] = a;
  }
  __syncthreads();
  if (t < 64){
    float a = bm2[t];
    #pragma unroll
    for (int p=0;p<8;p++) a += z2p[p][t];
    z2[t] = fmaxf(a, 0.f);
  }
  __syncthreads();
  { int n = t&127, part = t>>7;
    float a = 0.f;
    for (int f=part*16; f<part*16+16; f++) a += z2[f]*Wm3[f*128+n];
    z3p[part][n] = a;
  }
  __syncthreads();
  if (t < 128)
    out[t] = bm3[t] + z3p[0][t]+z3p[1][t]+z3p[2][t]+z3p[3][t];
}

extern "C" void kernel_launch(void* const* d_in, const int* in_sizes, int n_in,
                              void* d_out, int out_size, void* d_ws, size_t ws_size,
                              hipStream_t stream){
  (void)in_sizes; (void)n_in; (void)out_size; (void)ws_size;
  const float* x   = (const float*)d_in[0];
  const int*   ei  = (const int*)d_in[1];
  const float* ea  = (const float*)d_in[2];
  const float* W0  = (const float*)d_in[3];
  const float* as0 = (const float*)d_in[4];
  const float* ad0 = (const float*)d_in[5];
  const float* We0 = (const float*)d_in[6];
  const float* ae0 = (const float*)d_in[7];
  const float* b0  = (const float*)d_in[8];
  const float* W1  = (const float*)d_in[9];
  const float* as1 = (const float*)d_in[10];
  const float* ad1 = (const float*)d_in[11];
  const float* We1 = (const float*)d_in[12];
  const float* ae1 = (const float*)d_in[13];
  const float* b1  = (const float*)d_in[14];
  const float* Wm1 = (const float*)d_in[15];
  const float* bm1 = (const float*)d_in[16];
  const float* Wm2 = (const float*)d_in[17];
  const float* bm2 = (const float*)d_in[18];
  const float* Wm3 = (const float*)d_in[19];
  const float* bm3 = (const float*)d_in[20];
  float* out = (float*)d_out;

  char* ws = (char*)d_ws;
  size_t o = 0;
  auto alloc = [&](size_t bytes)->size_t{
    size_t r = o; o = (o + bytes + 255) & ~(size_t)255; return r;
  };
  size_t o_bufF   = alloc((size_t)N_*256*4);   // x1 (fp32), then h2 (fp16)
  size_t o_bufH   = alloc((size_t)N_*256*2);   // h0, then h1 (fp16)
  size_t o_als0   = alloc((size_t)N_*4*4);
  size_t o_ald0   = alloc((size_t)N_*4*4);
  size_t o_als1   = alloc((size_t)N_*4*4);
  size_t o_ald1   = alloc((size_t)N_*4*4);
  size_t o_rowptr = alloc((size_t)(N_+1)*4);
  size_t o_cursor = alloc((size_t)N_*4);
  size_t o_csrsrc = alloc((size_t)E_*4);
  size_t o_ale    = alloc((size_t)E_*8*2);     // 16B/edge fp16: [ale0 x4 | ale1 x4]
  size_t o_sarr   = alloc((size_t)N_*4);
  size_t o_Bhi    = alloc((size_t)256*256*2);
  size_t o_Blo    = alloc((size_t)256*256*2);
  size_t o_bsum   = alloc(256*4);
  size_t o_bpre   = alloc(256*4);
  // --- zero block ---
  size_t zstart   = o;
  size_t o_deg    = alloc((size_t)N_*4);
  size_t o_sumea  = alloc(16);
  size_t o_sumpool= alloc(256*4);
  size_t o_maxkey = alloc(256*4);
  size_t o_attpool= alloc(256*4);
  size_t o_smax   = alloc(4);
  size_t o_ssum   = alloc(4);
  size_t zend     = o;
  size_t o_small  = alloc(40*4);

  float*  bufF   = (float*)(ws + o_bufF);
  __half* bufH   = (__half*)(ws + o_bufH);
  __half* h2h    = (__half*)(ws + o_bufF);     // reuse bufF region for fp16 h2
  float* pals0  = (float*)(ws + o_als0);
  float* pald0  = (float*)(ws + o_ald0);
  float* pals1  = (float*)(ws + o_als1);
  float* pald1  = (float*)(ws + o_ald1);
  int*   rowptr = (int*)(ws + o_rowptr);
  int*   cursor = (int*)(ws + o_cursor);
  int*   csrsrc = (int*)(ws + o_csrsrc);
  __half* aleh  = (__half*)(ws + o_ale);
  float* sarr   = (float*)(ws + o_sarr);
  ushort* Bhi   = (ushort*)(ws + o_Bhi);
  ushort* Blo   = (ushort*)(ws + o_Blo);
  int*   bsum   = (int*)(ws + o_bsum);
  int*   bpre   = (int*)(ws + o_bpre);
  int*   deg    = (int*)(ws + o_deg);
  float* sumea  = (float*)(ws + o_sumea);
  float* sumpool= (float*)(ws + o_sumpool);
  unsigned* maxkey = (unsigned*)(ws + o_maxkey);
  float* attpool= (float*)(ws + o_attpool);
  unsigned* smax= (unsigned*)(ws + o_smax);
  float* ssum   = (float*)(ws + o_ssum);
  float* small  = (float*)(ws + o_small);

  hipMemsetAsync(ws + zstart, 0, zend - zstart, stream);

  int eb = (int)((E_ + 255)/256);          // 3125
  int nb_wave = (int)((N_*64 + 255)/256);  // 12500 (one wave per node)
  int gb = (int)((N_ + 31)/32);            // 1563 gemm blocks
  int sb = (int)((N_ + 255)/256);          // 196 scan blocks

  k_pre    <<<eb, 256, 0, stream>>>(ei, deg, ea, sumea, W1, Bhi, Blo);
  k_scan1  <<<sb, 256, 0, stream>>>(deg, bsum);
  k_scan2  <<<1, 256, 0, stream>>>(bsum, bpre, sb, rowptr,
                                   We0, ae0, We1, ae1, sumea, small);
  k_scan3  <<<sb, 256, 0, stream>>>(deg, bpre, rowptr, cursor);
  k_scatter<<<eb, 256, 0, stream>>>(ei, ea, cursor, csrsrc, aleh, small);
  k_h0     <<<nb_wave, 256, 0, stream>>>(x, W0, as0, ad0, bufH, pals0, pald0);
  k_agg<float,true>  <<<nb_wave, 256, 0, stream>>>(bufH, pals0, pald0, rowptr, csrsrc,
                                         aleh + 0, small, 32, b0, bufF);   // x1 fp32
  k_gemm   <<<gb, 256, 0, stream>>>(bufF, Bhi, Blo, bufH, as1, ad1, pals1, pald1);
  k_agg<__half,false><<<nb_wave, 256, 0, stream>>>(bufH, pals1, pald1, rowptr, csrsrc,
                                         aleh + 4, small, 36, b1, h2h);    // h2 fp16
  k_pool1  <<<256, 256, 0, stream>>>(h2h, sumpool, maxkey);
  k_atts   <<<1024, 256, 0, stream>>>(h2h, sumpool, sarr, smax);
  k_attd   <<<128, 256, 0, stream>>>(sarr, smax, ssum);
  k_attp   <<<256, 256, 0, stream>>>(h2h, sarr, smax, ssum, attpool);
  k_mlp    <<<1, 512, 0, stream>>>(sumpool, maxkey, attpool,
                                   Wm1, bm1, Wm2, bm2, Wm3, bm3, out);
}